// Round 3
// baseline (344.464 us; speedup 1.0000x reference)
//
#include <hip/hip_runtime.h>
#include <cstddef>

#define NB   32
#define CTXD 1024
#define FFD  8192
#define HD   256
#define WD   256
#define NPIX 65536
#define EPSF 1e-12f

// ---------- helpers ----------

__device__ __forceinline__ float ftanh(float x){
  float ax = fabsf(x);
  float e  = __expf(2.0f*ax);
  float r  = 1.0f - 2.0f*__builtin_amdgcn_rcpf(e + 1.0f);
  return copysignf(r, x);
}

__device__ __forceinline__ void block_reduce4(float& a, float& b, float& c, float& d){
  for (int off = 32; off > 0; off >>= 1){
    a += __shfl_down(a, off); b += __shfl_down(b, off);
    c += __shfl_down(c, off); d += __shfl_down(d, off);
  }
  __shared__ float lds[16];
  int wid = threadIdx.x >> 6, lane = threadIdx.x & 63;
  if (lane == 0){ lds[wid*4+0]=a; lds[wid*4+1]=b; lds[wid*4+2]=c; lds[wid*4+3]=d; }
  __syncthreads();
  a = (lds[0]+lds[4])+(lds[8]+lds[12]);
  b = (lds[1]+lds[5])+(lds[9]+lds[13]);
  c = (lds[2]+lds[6])+(lds[10]+lds[14]);
  d = (lds[3]+lds[7])+(lds[11]+lds[15]);
}

// ---------- kernels ----------

// Tiled GEMM: Cp[z][kc][f][b] = sum over k-chunk of W[f][k]*A[b][k].
// Block tile 256 feat x 32 batch, BK=32, per-thread 8f x 4b.
__global__ __launch_bounds__(256) void k_gemm_tiled(
    const float* __restrict__ A, const float* __restrict__ W0,
    const float* __restrict__ W1, float* __restrict__ Cp,
    int K, int kend, size_t zstride){
  __shared__ float As[32][36];
  __shared__ float Bs[256][36];
  int n0 = blockIdx.x * 256;
  int kc = blockIdx.y;
  const float* __restrict__ W = blockIdx.z ? W1 : W0;
  float* __restrict__ C = Cp + (size_t)blockIdx.z*zstride + (size_t)kc*(FFD*32);
  int t  = threadIdx.x;
  int rf = t >> 3, cb = t & 7;          // rf 0..31, cb 0..7
  float acc[8][4] = {{0.f}};
  for (int kit = 0; kit < kend; ++kit){
    int kbase = (kc*kend + kit)*32;
    *(float4*)(&As[rf][cb*4]) =
        *(const float4*)(A + (size_t)rf*K + kbase + cb*4);
    #pragma unroll
    for (int p = 0; p < 8; ++p){
      int row = rf + 32*p;
      *(float4*)(&Bs[row][cb*4]) =
          *(const float4*)(W + (size_t)(n0+row)*K + kbase + cb*4);
    }
    __syncthreads();
    #pragma unroll
    for (int kk = 0; kk < 32; kk += 4){
      float4 av[4], wv[8];
      #pragma unroll
      for (int i = 0; i < 4; ++i) av[i] = *(const float4*)(&As[cb + 8*i][kk]);
      #pragma unroll
      for (int j = 0; j < 8; ++j) wv[j] = *(const float4*)(&Bs[rf + 32*j][kk]);
      #pragma unroll
      for (int j = 0; j < 8; ++j)
        #pragma unroll
        for (int i = 0; i < 4; ++i)
          acc[j][i] += wv[j].x*av[i].x + wv[j].y*av[i].y
                     + wv[j].z*av[i].z + wv[j].w*av[i].w;
    }
    __syncthreads();
  }
  #pragma unroll
  for (int j = 0; j < 8; ++j)
    #pragma unroll
    for (int i = 0; i < 4; ++i)
      C[(size_t)(n0 + rf + 32*j)*32 + cb + 8*i] = acc[j][i];
}

// reduce for GEMM1 (both matrices) + zero-init red[]
__global__ __launch_bounds__(256) void k_reduce1(
    const float* __restrict__ Cp, const float* __restrict__ bin,
    const float* __restrict__ bg, float* __restrict__ xtT,
    float* __restrict__ xgT, float* __restrict__ red){
  if (blockIdx.x == 0 && threadIdx.x < 64) red[threadIdx.x] = 0.0f;
  int g = blockIdx.x*256 + threadIdx.x;          // 524288
  int m = g >> 18, idx = g & 262143;
  int f = idx >> 5;
  const float* __restrict__ cp = Cp + (size_t)m*(8ull*FFD*32);
  float s = (m ? bg : bin)[f];
  #pragma unroll
  for (int sI = 0; sI < 8; ++sI) s += cp[(size_t)sI*(FFD*32) + idx];
  (m ? xgT : xtT)[idx] = s;
}

// reduce for GEMM2
__global__ __launch_bounds__(256) void k_reduce2(
    const float* __restrict__ Cp, const float* __restrict__ bias,
    float* __restrict__ outT){
  int g = blockIdx.x*256 + threadIdx.x;          // 262144
  int f = g >> 5;
  float s = bias[f];
  #pragma unroll
  for (int sI = 0; sI < 16; ++sI) s += Cp[(size_t)sI*(FFD*32) + g];
  outT[g] = s;
}

// norm over 2048-groups (ddof=1); ctx_in = nt * tanh(ng)   [B][FF]
__global__ __launch_bounds__(256) void k_normgate(
    const float* __restrict__ xtT, const float* __restrict__ xgT, float* __restrict__ ctx_in){
  int b = blockIdx.x >> 2, g = blockIdx.x & 3;
  int t = threadIdx.x;
  int fbase = g*2048;
  float vt[8], vg[8];
  float st=0.f, sst=0.f, sg=0.f, ssg=0.f;
  #pragma unroll
  for (int i = 0; i < 8; ++i){
    int f = fbase + i*256 + t;
    float a = xtT[f*NB + b];
    float c = xgT[f*NB + b];
    vt[i]=a; vg[i]=c;
    st += a; sst += a*a; sg += c; ssg += c*c;
  }
  block_reduce4(st, sst, sg, ssg);
  float mt = st * (1.0f/2048.0f);
  float it = rsqrtf((sst - st*mt) * (1.0f/2047.0f) + EPSF);
  float mg = sg * (1.0f/2048.0f);
  float ig = rsqrtf((ssg - sg*mg) * (1.0f/2047.0f) + EPSF);
  #pragma unroll
  for (int i = 0; i < 8; ++i){
    int f = fbase + i*256 + t;
    float nt = (vt[i]-mt)*it;
    float ng = (vg[i]-mg)*ig;
    ctx_in[b*FFD + f] = nt * ftanh(ng);
  }
}

// norm over 512-groups (ddof=1) -> modc [B][16][512]
__global__ __launch_bounds__(256) void k_norm512(
    const float* __restrict__ ctx2T, float* __restrict__ modc){
  int b = blockIdx.x >> 4, kr = blockIdx.x & 15;
  int t = threadIdx.x;
  int base = kr*512;
  float v0 = ctx2T[(base + t      )*NB + b];
  float v1 = ctx2T[(base + 256 + t)*NB + b];
  float s = v0+v1, ss = v0*v0 + v1*v1, d0=0.f, d1=0.f;
  block_reduce4(s, ss, d0, d1);
  float m   = s * (1.0f/512.0f);
  float inv = rsqrtf((ss - s*m) * (1.0f/511.0f) + EPSF);
  modc[b*FFD + base + t      ] = (v0-m)*inv;
  modc[b*FFD + base + 256 + t] = (v1-m)*inv;
}

// pixel pass 1: tanh outer products, channel mix, store planes + per-batch max
__global__ __launch_bounds__(256) void k_pixel1(
    const float* __restrict__ modc,
    const float* __restrict__ convw, const float* __restrict__ convb,
    const float* __restrict__ wmod, const float* __restrict__ wstat,
    float* __restrict__ msr, float* __restrict__ msi,
    float* __restrict__ ppr, float* __restrict__ ppi,
    float* __restrict__ red){
  int b = blockIdx.x >> 4, chunk = blockIdx.x & 15;
  int t = threadIdx.x;
  __shared__ float lds[16*512];
  #pragma unroll
  for (int i = 0; i < 8; ++i){
    float4 v = *(const float4*)(modc + (size_t)b*FFD + (i*256 + t)*4);
    *(float4*)(lds + (i*256 + t)*4) = v;
  }
  float cw0 = convw[0]+convw[4]+convw[8]+convw[12];
  float cw1 = convw[1]+convw[5]+convw[9]+convw[13];
  float cw2 = convw[2]+convw[6]+convw[10]+convw[14];
  float cw3 = convw[3]+convw[7]+convw[11]+convw[15];
  float cb  = convb[0]+convb[1]+convb[2]+convb[3];
  __syncthreads();
  int w = t;
  float mxs = 0.f, mxp = 0.f;
  for (int it = 0; it < 16; ++it){
    int h = chunk*16 + it;
    int pix = h*WD + w;
    float sk[4];
    #pragma unroll
    for (int k = 0; k < 4; ++k){
      float acc = 0.f;
      #pragma unroll
      for (int r = 0; r < 4; ++r){
        int kr = k*4 + r;
        float u  = lds[kr*512 + h];
        float vv = lds[kr*512 + 256 + w];
        float tt = ftanh(u*vv);
        float cwr = (r==0)?cw0:(r==1)?cw1:(r==2)?cw2:cw3;
        acc += (k==0) ? cwr*tt : tt;
      }
      sk[k] = acc;
    }
    sk[0] += cb;
    float m0 = sk[0]*wmod[0*NPIX+pix];
    float m1 = sk[1]*wmod[1*NPIX+pix];
    float m2 = sk[2]*wmod[2*NPIX+pix];
    float m3 = sk[3]*wmod[3*NPIX+pix];
    float2 A1 = *(const float2*)(wstat + (size_t)(NPIX + pix)*2);
    float r_ = A1.x*m0 - A1.y*m1;
    float i_ = A1.x*m1 - A1.y*m0;
    size_t o = (size_t)b*NPIX + pix;
    msr[o]=r_; msi[o]=i_; ppr[o]=m2; ppi[o]=m3;
    float as = sqrtf(r_*r_ + i_*i_ + EPSF);
    float ap = sqrtf(m2*m2 + m3*m3 + EPSF);
    mxs = fmaxf(mxs, as); mxp = fmaxf(mxp, ap);
  }
  for (int off = 32; off > 0; off >>= 1){
    mxs = fmaxf(mxs, __shfl_down(mxs, off));
    mxp = fmaxf(mxp, __shfl_down(mxp, off));
  }
  __shared__ float lred[8];
  int wid = t >> 6, lane = t & 63;
  if (lane == 0){ lred[wid] = mxs; lred[4+wid] = mxp; }
  __syncthreads();
  if (t == 0){
    float a = fmaxf(fmaxf(lred[0],lred[1]), fmaxf(lred[2],lred[3]));
    float p = fmaxf(fmaxf(lred[4],lred[5]), fmaxf(lred[6],lred[7]));
    atomicMax((int*)&red[b],    __float_as_int(a));
    atomicMax((int*)&red[32+b], __float_as_int(p));
  }
}

// pixel pass 2: deterministic partial sums of |mod_scaled|
__global__ __launch_bounds__(256) void k_magsum(
    const float* __restrict__ msr, const float* __restrict__ msi,
    const float* __restrict__ red, float* __restrict__ magpart){
  int b = blockIdx.x >> 5, chunk = blockIdx.x & 31;
  int t = threadIdx.x;
  float maxs = red[b];
  float sum = 0.f;
  #pragma unroll
  for (int i = 0; i < 8; ++i){
    int pix = chunk*2048 + i*256 + t;
    size_t o = (size_t)b*NPIX + pix;
    float r_ = msr[o], i_ = msi[o];
    float sq = r_*r_ + i_*i_;
    float as = sqrtf(sq + EPSF);
    float hs = as/(maxs + EPSF);
    float tt = hs/(as + EPSF);
    sum += sqrtf(tt*tt*sq + EPSF);
  }
  for (int off = 32; off > 0; off >>= 1) sum += __shfl_down(sum, off);
  __shared__ float lr[4];
  int wid = t >> 6, lane = t & 63;
  if (lane == 0) lr[wid] = sum;
  __syncthreads();
  if (t == 0) magpart[b*32 + chunk] = (lr[0]+lr[1])+(lr[2]+lr[3]);
}

// final combine; folds the per-batch mag finalize (reads 32 partials per block)
__global__ __launch_bounds__(256) void k_final(
    const float* __restrict__ msr, const float* __restrict__ msi,
    const float* __restrict__ ppr, const float* __restrict__ ppi,
    const float* __restrict__ wstat, const float* __restrict__ red,
    const float* __restrict__ magpart, float* __restrict__ out){
  int g = blockIdx.x*256 + threadIdx.x;
  int b = g >> 16, pix = g & (NPIX-1);
  __shared__ float s_im;
  if (threadIdx.x < 32){
    float v = magpart[b*32 + threadIdx.x];
    for (int off = 16; off > 0; off >>= 1) v += __shfl_down(v, off);
    if (threadIdx.x == 0) s_im = rsqrtf(v*(1.0f/65536.0f) + EPSF);
  }
  __syncthreads();
  float im = s_im;
  size_t o = (size_t)b*NPIX + pix;
  float maxs = red[b], maxp = red[32+b];
  float r_ = msr[o], i_ = msi[o], p_ = ppr[o], q_ = ppi[o];
  float as = sqrtf(r_*r_ + i_*i_ + EPSF);
  float fs = (as/(maxs+EPSF))/(as+EPSF)*im;
  float2 A0 = *(const float2*)(wstat + (size_t)pix*2);
  float mwr = A0.x + fs*r_;
  float mwi = A0.y + fs*i_;
  float ap = sqrtf(p_*p_ + q_*q_ + EPSF);
  float fp = (ap/(maxp+EPSF))/(ap+EPSF);
  float mpr = fp*p_, mpi = fp*q_;
  float den = sqrtf(mpr*mpr + mpi*mpi + EPSF);
  out[o] = (mwr*mpr + mwi*mpi)/den;
}

// ---------- launch ----------

extern "C" void kernel_launch(void* const* d_in, const int* in_sizes, int n_in,
                              void* d_out, int out_size, void* d_ws, size_t ws_size,
                              hipStream_t stream){
  const float* x     = (const float*)d_in[0];
  const float* Win   = (const float*)d_in[1];
  const float* bin   = (const float*)d_in[2];
  const float* Wg    = (const float*)d_in[3];
  const float* bg    = (const float*)d_in[4];
  const float* Wt    = (const float*)d_in[5];
  const float* bt    = (const float*)d_in[6];
  const float* convw = (const float*)d_in[7];
  const float* convb = (const float*)d_in[8];
  const float* wstat = (const float*)d_in[9];
  const float* wmod  = (const float*)d_in[10];
  float* out = (float*)d_out;
  float* ws  = (float*)d_ws;

  float* xtT     = ws;                   // [FF][B]   262144
  float* xgT     = ws + 262144;
  float* ctx_in  = ws + 524288;          // [B][FF]
  float* ctx2T   = ws + 786432;          // [FF][B]
  float* modc    = ws + 1048576;         // [B][16][512]
  float* msr     = ws + 1310720;         // [B][NPIX] x4 planes
  float* msi     = ws + 3407872;
  float* ppr     = ws + 5505024;
  float* ppi     = ws + 7602176;
  float* red     = ws + 9699328;         // max_s[32], max_p[32]
  float* magpart = ws + 9699392;         // [32][32]

  // GEMM partials alias pixel planes (free until k_pixel1):
  float* Cp2 = msr;   // [16][FF][32] = 4M floats -> msr+msi
  float* Cp1 = ppr;   // [2][8][FF][32] = 4M floats -> ppr+ppi

  // GEMM1: both matrices, K=1024, split-K 8 (kchunk=128)
  k_gemm_tiled<<<dim3(32,8,2), 256, 0, stream>>>(x, Win, Wg, Cp1, CTXD, 4, 8ull*FFD*32);
  k_reduce1   <<<2048, 256, 0, stream>>>(Cp1, bin, bg, xtT, xgT, red);
  k_normgate  <<<128,  256, 0, stream>>>(xtT, xgT, ctx_in);
  // GEMM2: K=8192, split-K 16 (kchunk=512)
  k_gemm_tiled<<<dim3(32,16,1), 256, 0, stream>>>(ctx_in, Wt, Wt, Cp2, FFD, 16, 0);
  k_reduce2   <<<1024, 256, 0, stream>>>(Cp2, bt, ctx2T);
  k_norm512   <<<512,  256, 0, stream>>>(ctx2T, modc);
  k_pixel1    <<<512,  256, 0, stream>>>(modc, convw, convb, wmod, wstat,
                                         msr, msi, ppr, ppi, red);
  k_magsum    <<<1024, 256, 0, stream>>>(msr, msi, red, magpart);
  k_final     <<<8192, 256, 0, stream>>>(msr, msi, ppr, ppi, wstat, red, magpart, out);
}

// Round 4
// 233.607 us; speedup vs baseline: 1.4745x; 1.4745x over previous
//
#include <hip/hip_runtime.h>
#include <cstddef>

#define NB   32
#define CTXD 1024
#define FFD  8192
#define HD   256
#define WD   256
#define NPIX 65536
#define EPSF 1e-12f

// ---------- helpers ----------

__device__ __forceinline__ float ftanh(float x){
  float ax = fabsf(x);
  float e  = __expf(2.0f*ax);
  float r  = 1.0f - 2.0f*__builtin_amdgcn_rcpf(e + 1.0f);
  return copysignf(r, x);
}

__device__ __forceinline__ void block_reduce4(float& a, float& b, float& c, float& d){
  for (int off = 32; off > 0; off >>= 1){
    a += __shfl_down(a, off); b += __shfl_down(b, off);
    c += __shfl_down(c, off); d += __shfl_down(d, off);
  }
  __shared__ float lds[16];
  int wid = threadIdx.x >> 6, lane = threadIdx.x & 63;
  if (lane == 0){ lds[wid*4+0]=a; lds[wid*4+1]=b; lds[wid*4+2]=c; lds[wid*4+3]=d; }
  __syncthreads();
  a = (lds[0]+lds[4])+(lds[8]+lds[12]);
  b = (lds[1]+lds[5])+(lds[9]+lds[13]);
  c = (lds[2]+lds[6])+(lds[10]+lds[14]);
  d = (lds[3]+lds[7])+(lds[11]+lds[15]);
}

// ---------- kernels ----------

// Tiled GEMM with register prefetch (T14): tile 128 feat x 32 batch, BK=32,
// per-thread 4f x 4b. Cp[z][kc][f][b]. grid = (64, S, nmat).
__global__ __launch_bounds__(256) void k_gemm_tiled(
    const float* __restrict__ A, const float* __restrict__ W0,
    const float* __restrict__ W1, float* __restrict__ Cp,
    int K, int kend, size_t zstride){
  __shared__ float As[32][40];   // stride 40: compute reads 2-way max (free)
  __shared__ float Bs[128][40];
  int n0 = blockIdx.x * 128;
  int kc = blockIdx.y;
  const float* __restrict__ W = blockIdx.z ? W1 : W0;
  float* __restrict__ C = Cp + (size_t)blockIdx.z*zstride + (size_t)kc*(FFD*32);
  int t  = threadIdx.x;
  int rf = t >> 3, cb = t & 7;          // rf 0..31, cb 0..7
  const float* Arow = A + (size_t)rf*K + cb*4;
  const float* Wrow = W + (size_t)(n0+rf)*K + cb*4;
  float acc[4][4] = {{0.f}};
  int kb0 = kc*kend*32;
  // prefetch kit 0
  float4 apre = *(const float4*)(Arow + kb0);
  float4 wpre[4];
  #pragma unroll
  for (int p = 0; p < 4; ++p)
    wpre[p] = *(const float4*)(Wrow + (size_t)(32*p)*K + kb0);
  for (int kit = 0; kit < kend; ++kit){
    if (kit) __syncthreads();
    *(float4*)(&As[rf][cb*4]) = apre;
    #pragma unroll
    for (int p = 0; p < 4; ++p)
      *(float4*)(&Bs[rf+32*p][cb*4]) = wpre[p];
    __syncthreads();
    if (kit + 1 < kend){                 // issue next-kit loads early; they
      int kb = kb0 + (kit+1)*32;         // complete under the FMA phase
      apre = *(const float4*)(Arow + kb);
      #pragma unroll
      for (int p = 0; p < 4; ++p)
        wpre[p] = *(const float4*)(Wrow + (size_t)(32*p)*K + kb);
    }
    #pragma unroll
    for (int kk = 0; kk < 32; kk += 4){
      float4 av[4], wv[4];
      #pragma unroll
      for (int i = 0; i < 4; ++i) av[i] = *(const float4*)(&As[cb + 8*i][kk]);
      #pragma unroll
      for (int j = 0; j < 4; ++j) wv[j] = *(const float4*)(&Bs[rf + 32*j][kk]);
      #pragma unroll
      for (int j = 0; j < 4; ++j)
        #pragma unroll
        for (int i = 0; i < 4; ++i)
          acc[j][i] += wv[j].x*av[i].x + wv[j].y*av[i].y
                     + wv[j].z*av[i].z + wv[j].w*av[i].w;
    }
  }
  #pragma unroll
  for (int j = 0; j < 4; ++j)
    #pragma unroll
    for (int i = 0; i < 4; ++i)
      C[(size_t)(n0 + rf + 32*j)*32 + cb + 8*i] = acc[j][i];
}

// reduce for GEMM1 (both matrices) + zero-init red[]
__global__ __launch_bounds__(256) void k_reduce1(
    const float* __restrict__ Cp, const float* __restrict__ bin,
    const float* __restrict__ bg, float* __restrict__ xtT,
    float* __restrict__ xgT, float* __restrict__ red){
  if (blockIdx.x == 0 && threadIdx.x < 64) red[threadIdx.x] = 0.0f;
  int g = blockIdx.x*256 + threadIdx.x;          // 524288
  int m = g >> 18, idx = g & 262143;
  int f = idx >> 5;
  const float* __restrict__ cp = Cp + (size_t)m*(8ull*FFD*32);
  float s = (m ? bg : bin)[f];
  #pragma unroll
  for (int sI = 0; sI < 8; ++sI) s += cp[(size_t)sI*(FFD*32) + idx];
  (m ? xgT : xtT)[idx] = s;
}

// reduce for GEMM2 (S=32)
__global__ __launch_bounds__(256) void k_reduce2(
    const float* __restrict__ Cp, const float* __restrict__ bias,
    float* __restrict__ outT){
  int g = blockIdx.x*256 + threadIdx.x;          // 262144
  int f = g >> 5;
  float s = bias[f];
  #pragma unroll
  for (int sI = 0; sI < 32; ++sI) s += Cp[(size_t)sI*(FFD*32) + g];
  outT[g] = s;
}

// norm over 2048-groups (ddof=1); ctx_in = nt * tanh(ng)   [B][FF]
__global__ __launch_bounds__(256) void k_normgate(
    const float* __restrict__ xtT, const float* __restrict__ xgT, float* __restrict__ ctx_in){
  int b = blockIdx.x >> 2, g = blockIdx.x & 3;
  int t = threadIdx.x;
  int fbase = g*2048;
  float vt[8], vg[8];
  float st=0.f, sst=0.f, sg=0.f, ssg=0.f;
  #pragma unroll
  for (int i = 0; i < 8; ++i){
    int f = fbase + i*256 + t;
    float a = xtT[f*NB + b];
    float c = xgT[f*NB + b];
    vt[i]=a; vg[i]=c;
    st += a; sst += a*a; sg += c; ssg += c*c;
  }
  block_reduce4(st, sst, sg, ssg);
  float mt = st * (1.0f/2048.0f);
  float it = rsqrtf((sst - st*mt) * (1.0f/2047.0f) + EPSF);
  float mg = sg * (1.0f/2048.0f);
  float ig = rsqrtf((ssg - sg*mg) * (1.0f/2047.0f) + EPSF);
  #pragma unroll
  for (int i = 0; i < 8; ++i){
    int f = fbase + i*256 + t;
    float nt = (vt[i]-mt)*it;
    float ng = (vg[i]-mg)*ig;
    ctx_in[b*FFD + f] = nt * ftanh(ng);
  }
}

// norm over 512-groups (ddof=1) -> modc [B][16][512]
__global__ __launch_bounds__(256) void k_norm512(
    const float* __restrict__ ctx2T, float* __restrict__ modc){
  int b = blockIdx.x >> 4, kr = blockIdx.x & 15;
  int t = threadIdx.x;
  int base = kr*512;
  float v0 = ctx2T[(base + t      )*NB + b];
  float v1 = ctx2T[(base + 256 + t)*NB + b];
  float s = v0+v1, ss = v0*v0 + v1*v1, d0=0.f, d1=0.f;
  block_reduce4(s, ss, d0, d1);
  float m   = s * (1.0f/512.0f);
  float inv = rsqrtf((ss - s*m) * (1.0f/511.0f) + EPSF);
  modc[b*FFD + base + t      ] = (v0-m)*inv;
  modc[b*FFD + base + 256 + t] = (v1-m)*inv;
}

// pixel pass 1: tanh outer products, channel mix, store planes + per-batch max
__global__ __launch_bounds__(256) void k_pixel1(
    const float* __restrict__ modc,
    const float* __restrict__ convw, const float* __restrict__ convb,
    const float* __restrict__ wmod, const float* __restrict__ wstat,
    float* __restrict__ msr, float* __restrict__ msi,
    float* __restrict__ ppr, float* __restrict__ ppi,
    float* __restrict__ red){
  int b = blockIdx.x >> 4, chunk = blockIdx.x & 15;
  int t = threadIdx.x;
  __shared__ float lds[16*512];
  #pragma unroll
  for (int i = 0; i < 8; ++i){
    float4 v = *(const float4*)(modc + (size_t)b*FFD + (i*256 + t)*4);
    *(float4*)(lds + (i*256 + t)*4) = v;
  }
  float cw0 = convw[0]+convw[4]+convw[8]+convw[12];
  float cw1 = convw[1]+convw[5]+convw[9]+convw[13];
  float cw2 = convw[2]+convw[6]+convw[10]+convw[14];
  float cw3 = convw[3]+convw[7]+convw[11]+convw[15];
  float cb  = convb[0]+convb[1]+convb[2]+convb[3];
  __syncthreads();
  int w = t;
  float mxs = 0.f, mxp = 0.f;
  for (int it = 0; it < 16; ++it){
    int h = chunk*16 + it;
    int pix = h*WD + w;
    float sk[4];
    #pragma unroll
    for (int k = 0; k < 4; ++k){
      float acc = 0.f;
      #pragma unroll
      for (int r = 0; r < 4; ++r){
        int kr = k*4 + r;
        float u  = lds[kr*512 + h];
        float vv = lds[kr*512 + 256 + w];
        float tt = ftanh(u*vv);
        float cwr = (r==0)?cw0:(r==1)?cw1:(r==2)?cw2:cw3;
        acc += (k==0) ? cwr*tt : tt;
      }
      sk[k] = acc;
    }
    sk[0] += cb;
    float m0 = sk[0]*wmod[0*NPIX+pix];
    float m1 = sk[1]*wmod[1*NPIX+pix];
    float m2 = sk[2]*wmod[2*NPIX+pix];
    float m3 = sk[3]*wmod[3*NPIX+pix];
    float2 A1 = *(const float2*)(wstat + (size_t)(NPIX + pix)*2);
    float r_ = A1.x*m0 - A1.y*m1;
    float i_ = A1.x*m1 - A1.y*m0;
    size_t o = (size_t)b*NPIX + pix;
    msr[o]=r_; msi[o]=i_; ppr[o]=m2; ppi[o]=m3;
    float as = sqrtf(r_*r_ + i_*i_ + EPSF);
    float ap = sqrtf(m2*m2 + m3*m3 + EPSF);
    mxs = fmaxf(mxs, as); mxp = fmaxf(mxp, ap);
  }
  for (int off = 32; off > 0; off >>= 1){
    mxs = fmaxf(mxs, __shfl_down(mxs, off));
    mxp = fmaxf(mxp, __shfl_down(mxp, off));
  }
  __shared__ float lred[8];
  int wid = t >> 6, lane = t & 63;
  if (lane == 0){ lred[wid] = mxs; lred[4+wid] = mxp; }
  __syncthreads();
  if (t == 0){
    float a = fmaxf(fmaxf(lred[0],lred[1]), fmaxf(lred[2],lred[3]));
    float p = fmaxf(fmaxf(lred[4],lred[5]), fmaxf(lred[6],lred[7]));
    atomicMax((int*)&red[b],    __float_as_int(a));
    atomicMax((int*)&red[32+b], __float_as_int(p));
  }
}

// pixel pass 2: deterministic partial sums of |mod_scaled|
__global__ __launch_bounds__(256) void k_magsum(
    const float* __restrict__ msr, const float* __restrict__ msi,
    const float* __restrict__ red, float* __restrict__ magpart){
  int b = blockIdx.x >> 5, chunk = blockIdx.x & 31;
  int t = threadIdx.x;
  float maxs = red[b];
  float sum = 0.f;
  #pragma unroll
  for (int i = 0; i < 8; ++i){
    int pix = chunk*2048 + i*256 + t;
    size_t o = (size_t)b*NPIX + pix;
    float r_ = msr[o], i_ = msi[o];
    float sq = r_*r_ + i_*i_;
    float as = sqrtf(sq + EPSF);
    float hs = as/(maxs + EPSF);
    float tt = hs/(as + EPSF);
    sum += sqrtf(tt*tt*sq + EPSF);
  }
  for (int off = 32; off > 0; off >>= 1) sum += __shfl_down(sum, off);
  __shared__ float lr[4];
  int wid = t >> 6, lane = t & 63;
  if (lane == 0) lr[wid] = sum;
  __syncthreads();
  if (t == 0) magpart[b*32 + chunk] = (lr[0]+lr[1])+(lr[2]+lr[3]);
}

// final combine; folds the per-batch mag finalize
__global__ __launch_bounds__(256) void k_final(
    const float* __restrict__ msr, const float* __restrict__ msi,
    const float* __restrict__ ppr, const float* __restrict__ ppi,
    const float* __restrict__ wstat, const float* __restrict__ red,
    const float* __restrict__ magpart, float* __restrict__ out){
  int g = blockIdx.x*256 + threadIdx.x;
  int b = g >> 16, pix = g & (NPIX-1);
  __shared__ float s_im;
  if (threadIdx.x < 32){
    float v = magpart[b*32 + threadIdx.x];
    for (int off = 16; off > 0; off >>= 1) v += __shfl_down(v, off);
    if (threadIdx.x == 0) s_im = rsqrtf(v*(1.0f/65536.0f) + EPSF);
  }
  __syncthreads();
  float im = s_im;
  size_t o = (size_t)b*NPIX + pix;
  float maxs = red[b], maxp = red[32+b];
  float r_ = msr[o], i_ = msi[o], p_ = ppr[o], q_ = ppi[o];
  float as = sqrtf(r_*r_ + i_*i_ + EPSF);
  float fs = (as/(maxs+EPSF))/(as+EPSF)*im;
  float2 A0 = *(const float2*)(wstat + (size_t)pix*2);
  float mwr = A0.x + fs*r_;
  float mwi = A0.y + fs*i_;
  float ap = sqrtf(p_*p_ + q_*q_ + EPSF);
  float fp = (ap/(maxp+EPSF))/(ap+EPSF);
  float mpr = fp*p_, mpi = fp*q_;
  float den = sqrtf(mpr*mpr + mpi*mpi + EPSF);
  out[o] = (mwr*mpr + mwi*mpi)/den;
}

// ---------- launch ----------

extern "C" void kernel_launch(void* const* d_in, const int* in_sizes, int n_in,
                              void* d_out, int out_size, void* d_ws, size_t ws_size,
                              hipStream_t stream){
  const float* x     = (const float*)d_in[0];
  const float* Win   = (const float*)d_in[1];
  const float* bin   = (const float*)d_in[2];
  const float* Wg    = (const float*)d_in[3];
  const float* bg    = (const float*)d_in[4];
  const float* Wt    = (const float*)d_in[5];
  const float* bt    = (const float*)d_in[6];
  const float* convw = (const float*)d_in[7];
  const float* convb = (const float*)d_in[8];
  const float* wstat = (const float*)d_in[9];
  const float* wmod  = (const float*)d_in[10];
  float* out = (float*)d_out;
  float* ws  = (float*)d_ws;

  float* xtT     = ws;                   // [FF][B]
  float* xgT     = ws + 262144;
  float* ctx_in  = ws + 524288;          // [B][FF]
  float* ctx2T   = ws + 786432;          // [FF][B]
  float* modc    = ws + 1048576;         // [B][16][512]
  float* msr     = ws + 1310720;         // [B][NPIX] x4 planes
  float* msi     = ws + 3407872;
  float* ppr     = ws + 5505024;
  float* ppi     = ws + 7602176;
  float* red     = ws + 9699328;         // max_s[32], max_p[32]
  float* magpart = ws + 9699392;         // [32][32]

  // GEMM partials alias pixel planes (dead until k_pixel1):
  float* Cp2 = msr;   // [32][FF][32] = 8M floats -> all 4 planes (32 MB)
  float* Cp1 = ppr;   // [2][8][FF][32] = 4M floats -> ppr+ppi (16 MB)

  // GEMM1: both matrices, K=1024, split-K 8 (kchunk=128)
  k_gemm_tiled<<<dim3(64,8,2), 256, 0, stream>>>(x, Win, Wg, Cp1, CTXD, 4, 8ull*FFD*32);
  k_reduce1   <<<2048, 256, 0, stream>>>(Cp1, bin, bg, xtT, xgT, red);
  k_normgate  <<<128,  256, 0, stream>>>(xtT, xgT, ctx_in);
  // GEMM2: K=8192, split-K 32 (kchunk=256)
  k_gemm_tiled<<<dim3(64,32,1), 256, 0, stream>>>(ctx_in, Wt, Wt, Cp2, FFD, 8, 0);
  k_reduce2   <<<1024, 256, 0, stream>>>(Cp2, bt, ctx2T);
  k_norm512   <<<512,  256, 0, stream>>>(ctx2T, modc);
  k_pixel1    <<<512,  256, 0, stream>>>(modc, convw, convb, wmod, wstat,
                                         msr, msi, ppr, ppi, red);
  k_magsum    <<<1024, 256, 0, stream>>>(msr, msi, red, magpart);
  k_final     <<<8192, 256, 0, stream>>>(msr, msi, ppr, ppi, wstat, red, magpart, out);
}

// Round 6
// 229.336 us; speedup vs baseline: 1.5020x; 1.0186x over previous
//
#include <hip/hip_runtime.h>
#include <cstddef>

#define NB   32
#define CTXD 1024
#define FFD  8192
#define HD   256
#define WD   256
#define NPIX 65536
#define EPSF 1e-12f

typedef __attribute__((ext_vector_type(8))) short bf16x8;
typedef __attribute__((ext_vector_type(4))) float f32x4;

// ---------- helpers ----------

__device__ __forceinline__ float ftanh(float x){
  float ax = fabsf(x);
  float e  = __expf(2.0f*ax);
  float r  = 1.0f - 2.0f*__builtin_amdgcn_rcpf(e + 1.0f);
  return copysignf(r, x);
}

__device__ __forceinline__ unsigned short f2bf(float f){
  unsigned u = __float_as_uint(f);
  unsigned r = (u + 0x7FFFu + ((u >> 16) & 1u)) >> 16;   // RTNE
  return (unsigned short)r;
}
__device__ __forceinline__ float bf2f(unsigned short s){
  return __uint_as_float((unsigned)s << 16);
}

// split f32 -> 3 bf16 terms (residual ~2^-27 relative)
__device__ __forceinline__ void split3(float f, unsigned short& s0,
                                       unsigned short& s1, unsigned short& s2){
  s0 = f2bf(f);
  float r1 = f - bf2f(s0);
  s1 = f2bf(r1);
  float r2 = r1 - bf2f(s1);
  s2 = f2bf(r2);
}

__device__ __forceinline__ void block_reduce4(float& a, float& b, float& c, float& d){
  for (int off = 32; off > 0; off >>= 1){
    a += __shfl_down(a, off); b += __shfl_down(b, off);
    c += __shfl_down(c, off); d += __shfl_down(d, off);
  }
  __shared__ float lds[16];
  int wid = threadIdx.x >> 6, lane = threadIdx.x & 63;
  if (lane == 0){ lds[wid*4+0]=a; lds[wid*4+1]=b; lds[wid*4+2]=c; lds[wid*4+3]=d; }
  __syncthreads();
  a = (lds[0]+lds[4])+(lds[8]+lds[12]);
  b = (lds[1]+lds[5])+(lds[9]+lds[13]);
  c = (lds[2]+lds[6])+(lds[10]+lds[14]);
  d = (lds[3]+lds[7])+(lds[11]+lds[15]);
}

// ---------- kernels ----------

// split x [32][1024] f32 -> 3 bf16 planes, zero red[]
__global__ __launch_bounds__(256) void k_prep(
    const float* __restrict__ x, unsigned short* __restrict__ xh,
    unsigned short* __restrict__ xm, unsigned short* __restrict__ xl,
    float* __restrict__ red){
  int g = blockIdx.x*256 + threadIdx.x;      // 8192 threads x 4 elems
  if (g < 64) red[g] = 0.0f;
  float4 v = *(const float4*)(x + g*4);
  float vv[4] = {v.x, v.y, v.z, v.w};
  #pragma unroll
  for (int e = 0; e < 4; ++e){
    unsigned short s0, s1, s2;
    split3(vv[e], s0, s1, s2);
    xh[g*4+e] = s0; xm[g*4+e] = s1; xl[g*4+e] = s2;
  }
}

// Split-bf16 MFMA GEMM (f32-accurate): Cp[z][kc][f][b] = sum_k W[f][k]*ctx[b][k].
// W streamed f32, split to 3 bf16 in-register; ctx pre-split in 3 bf16 planes.
// 6 products (i+j<=2) x 2 batch-halves = 12 MFMA per K=32 chunk.
template<int KCHUNKS>
__global__ __launch_bounds__(256) void k_gemm_mfma(
    const float* __restrict__ W0, const float* __restrict__ W1,
    const unsigned short* __restrict__ B0, const unsigned short* __restrict__ B1,
    const unsigned short* __restrict__ B2,
    float* __restrict__ Cp, int K, size_t zstride){
  const float* __restrict__ W = blockIdx.z ? W1 : W0;
  int wave = threadIdx.x >> 6;
  int lane = threadIdx.x & 63;
  int f0   = blockIdx.x*64 + wave*16;
  int kc   = blockIdx.y;
  int row  = lane & 15;                 // A-row (feature) / B-col (batch)
  int kg   = lane >> 4;                 // k-group
  size_t kbase = (size_t)kc*KCHUNKS*32 + kg*8;
  const float* wrow = W + (size_t)(f0 + row)*K + kbase;
  size_t b0off = (size_t)row*K + kbase;        // batches 0..15
  size_t b1off = (size_t)(16+row)*K + kbase;   // batches 16..31
  f32x4 acc0 = {0.f,0.f,0.f,0.f}, acc1 = {0.f,0.f,0.f,0.f};
  // prefetch chunk 0
  float4 w0 = *(const float4*)(wrow), w1 = *(const float4*)(wrow + 4);
  bf16x8 p00 = *(const bf16x8*)(B0+b0off), p01 = *(const bf16x8*)(B1+b0off),
         p02 = *(const bf16x8*)(B2+b0off);
  bf16x8 p10 = *(const bf16x8*)(B0+b1off), p11 = *(const bf16x8*)(B1+b1off),
         p12 = *(const bf16x8*)(B2+b1off);
  for (int c = 0; c < KCHUNKS; ++c){
    float4 cw0 = w0, cw1 = w1;
    bf16x8 q00=p00, q01=p01, q02=p02, q10=p10, q11=p11, q12=p12;
    if (c + 1 < KCHUNKS){               // next-chunk loads complete under MFMA
      wrow += 32; b0off += 32; b1off += 32;
      w0 = *(const float4*)(wrow); w1 = *(const float4*)(wrow + 4);
      p00 = *(const bf16x8*)(B0+b0off); p01 = *(const bf16x8*)(B1+b0off);
      p02 = *(const bf16x8*)(B2+b0off);
      p10 = *(const bf16x8*)(B0+b1off); p11 = *(const bf16x8*)(B1+b1off);
      p12 = *(const bf16x8*)(B2+b1off);
    }
    bf16x8 a0, a1, a2;
    float wv[8] = {cw0.x,cw0.y,cw0.z,cw0.w,cw1.x,cw1.y,cw1.z,cw1.w};
    #pragma unroll
    for (int e = 0; e < 8; ++e){
      unsigned short s0, s1, s2;
      split3(wv[e], s0, s1, s2);
      a0[e]=(short)s0; a1[e]=(short)s1; a2[e]=(short)s2;
    }
    // D = sum_{i+j<=2} a_i * b_j  (interleave halves to break acc chains)
    acc0 = __builtin_amdgcn_mfma_f32_16x16x32_bf16(a0, q00, acc0, 0,0,0);
    acc1 = __builtin_amdgcn_mfma_f32_16x16x32_bf16(a0, q10, acc1, 0,0,0);
    acc0 = __builtin_amdgcn_mfma_f32_16x16x32_bf16(a0, q01, acc0, 0,0,0);
    acc1 = __builtin_amdgcn_mfma_f32_16x16x32_bf16(a0, q11, acc1, 0,0,0);
    acc0 = __builtin_amdgcn_mfma_f32_16x16x32_bf16(a1, q00, acc0, 0,0,0);
    acc1 = __builtin_amdgcn_mfma_f32_16x16x32_bf16(a1, q10, acc1, 0,0,0);
    acc0 = __builtin_amdgcn_mfma_f32_16x16x32_bf16(a0, q02, acc0, 0,0,0);
    acc1 = __builtin_amdgcn_mfma_f32_16x16x32_bf16(a0, q12, acc1, 0,0,0);
    acc0 = __builtin_amdgcn_mfma_f32_16x16x32_bf16(a1, q01, acc0, 0,0,0);
    acc1 = __builtin_amdgcn_mfma_f32_16x16x32_bf16(a1, q11, acc1, 0,0,0);
    acc0 = __builtin_amdgcn_mfma_f32_16x16x32_bf16(a2, q00, acc0, 0,0,0);
    acc1 = __builtin_amdgcn_mfma_f32_16x16x32_bf16(a2, q10, acc1, 0,0,0);
  }
  float* __restrict__ C = Cp + (size_t)blockIdx.z*zstride + (size_t)kc*(FFD*32);
  #pragma unroll
  for (int r = 0; r < 4; ++r){          // C/D: col=lane&15, row=(lane>>4)*4+r
    int f = f0 + kg*4 + r;
    C[(size_t)f*32 + row]      = acc0[r];
    C[(size_t)f*32 + 16 + row] = acc1[r];
  }
}

// reduce for GEMM1 (both matrices), S=4
__global__ __launch_bounds__(256) void k_reduce1(
    const float* __restrict__ Cp, const float* __restrict__ bin,
    const float* __restrict__ bg, float* __restrict__ xtT,
    float* __restrict__ xgT){
  int g = blockIdx.x*256 + threadIdx.x;          // 524288
  int m = g >> 18, idx = g & 262143;
  int f = idx >> 5;
  const float* __restrict__ cp = Cp + (size_t)m*(4ull*FFD*32);
  float s = (m ? bg : bin)[f];
  #pragma unroll
  for (int sI = 0; sI < 4; ++sI) s += cp[(size_t)sI*(FFD*32) + idx];
  (m ? xgT : xtT)[idx] = s;
}

// reduce for GEMM2, S=8
__global__ __launch_bounds__(256) void k_reduce2(
    const float* __restrict__ Cp, const float* __restrict__ bias,
    float* __restrict__ outT){
  int g = blockIdx.x*256 + threadIdx.x;          // 262144
  int f = g >> 5;
  float s = bias[f];
  #pragma unroll
  for (int sI = 0; sI < 8; ++sI) s += Cp[(size_t)sI*(FFD*32) + g];
  outT[g] = s;
}

// norm over 2048-groups (ddof=1); ctx = nt*tanh(ng) split into 3 bf16 planes
__global__ __launch_bounds__(256) void k_normgate(
    const float* __restrict__ xtT, const float* __restrict__ xgT,
    unsigned short* __restrict__ ch, unsigned short* __restrict__ cm,
    unsigned short* __restrict__ cl){
  int b = blockIdx.x >> 2, g = blockIdx.x & 3;
  int t = threadIdx.x;
  int fbase = g*2048;
  float vt[8], vg[8];
  float st=0.f, sst=0.f, sg=0.f, ssg=0.f;
  #pragma unroll
  for (int i = 0; i < 8; ++i){
    int f = fbase + i*256 + t;
    float a = xtT[f*NB + b];
    float c = xgT[f*NB + b];
    vt[i]=a; vg[i]=c;
    st += a; sst += a*a; sg += c; ssg += c*c;
  }
  block_reduce4(st, sst, sg, ssg);
  float mt = st * (1.0f/2048.0f);
  float it = rsqrtf((sst - st*mt) * (1.0f/2047.0f) + EPSF);
  float mg = sg * (1.0f/2048.0f);
  float ig = rsqrtf((ssg - sg*mg) * (1.0f/2047.0f) + EPSF);
  #pragma unroll
  for (int i = 0; i < 8; ++i){
    int f = fbase + i*256 + t;
    float nt = (vt[i]-mt)*it;
    float ng = (vg[i]-mg)*ig;
    float c  = nt * ftanh(ng);
    unsigned short s0, s1, s2;
    split3(c, s0, s1, s2);
    ch[b*FFD + f] = s0; cm[b*FFD + f] = s1; cl[b*FFD + f] = s2;
  }
}

// norm over 512-groups (ddof=1) -> modc [B][16][512]
__global__ __launch_bounds__(256) void k_norm512(
    const float* __restrict__ ctx2T, float* __restrict__ modc){
  int b = blockIdx.x >> 4, kr = blockIdx.x & 15;
  int t = threadIdx.x;
  int base = kr*512;
  float v0 = ctx2T[(base + t      )*NB + b];
  float v1 = ctx2T[(base + 256 + t)*NB + b];
  float s = v0+v1, ss = v0*v0 + v1*v1, d0=0.f, d1=0.f;
  block_reduce4(s, ss, d0, d1);
  float m   = s * (1.0f/512.0f);
  float inv = rsqrtf((ss - s*m) * (1.0f/511.0f) + EPSF);
  modc[b*FFD + base + t      ] = (v0-m)*inv;
  modc[b*FFD + base + 256 + t] = (v1-m)*inv;
}

// pixel pass 1: tanh outer products, channel mix, store planes + per-batch max
__global__ __launch_bounds__(256) void k_pixel1(
    const float* __restrict__ modc,
    const float* __restrict__ convw, const float* __restrict__ convb,
    const float* __restrict__ wmod, const float* __restrict__ wstat,
    float* __restrict__ msr, float* __restrict__ msi,
    float* __restrict__ ppr, float* __restrict__ ppi,
    float* __restrict__ red){
  int b = blockIdx.x >> 4, chunk = blockIdx.x & 15;
  int t = threadIdx.x;
  __shared__ float lds[16*512];
  #pragma unroll
  for (int i = 0; i < 8; ++i){
    float4 v = *(const float4*)(modc + (size_t)b*FFD + (i*256 + t)*4);
    *(float4*)(lds + (i*256 + t)*4) = v;
  }
  float cw0 = convw[0]+convw[4]+convw[8]+convw[12];
  float cw1 = convw[1]+convw[5]+convw[9]+convw[13];
  float cw2 = convw[2]+convw[6]+convw[10]+convw[14];
  float cw3 = convw[3]+convw[7]+convw[11]+convw[15];
  float cb  = convb[0]+convb[1]+convb[2]+convb[3];
  __syncthreads();
  int w = t;
  float mxs = 0.f, mxp = 0.f;
  for (int it = 0; it < 16; ++it){
    int h = chunk*16 + it;
    int pix = h*WD + w;
    float sk[4];
    #pragma unroll
    for (int k = 0; k < 4; ++k){
      float acc = 0.f;
      #pragma unroll
      for (int r = 0; r < 4; ++r){
        int kr = k*4 + r;
        float u  = lds[kr*512 + h];
        float vv = lds[kr*512 + 256 + w];
        float tt = ftanh(u*vv);
        float cwr = (r==0)?cw0:(r==1)?cw1:(r==2)?cw2:cw3;
        acc += (k==0) ? cwr*tt : tt;
      }
      sk[k] = acc;
    }
    sk[0] += cb;
    float m0 = sk[0]*wmod[0*NPIX+pix];
    float m1 = sk[1]*wmod[1*NPIX+pix];
    float m2 = sk[2]*wmod[2*NPIX+pix];
    float m3 = sk[3]*wmod[3*NPIX+pix];
    float2 A1 = *(const float2*)(wstat + (size_t)(NPIX + pix)*2);
    float r_ = A1.x*m0 - A1.y*m1;
    float i_ = A1.x*m1 - A1.y*m0;
    size_t o = (size_t)b*NPIX + pix;
    msr[o]=r_; msi[o]=i_; ppr[o]=m2; ppi[o]=m3;
    float as = sqrtf(r_*r_ + i_*i_ + EPSF);
    float ap = sqrtf(m2*m2 + m3*m3 + EPSF);
    mxs = fmaxf(mxs, as); mxp = fmaxf(mxp, ap);
  }
  for (int off = 32; off > 0; off >>= 1){
    mxs = fmaxf(mxs, __shfl_down(mxs, off));
    mxp = fmaxf(mxp, __shfl_down(mxp, off));
  }
  __shared__ float lred[8];
  int wid = t >> 6, lane = t & 63;
  if (lane == 0){ lred[wid] = mxs; lred[4+wid] = mxp; }
  __syncthreads();
  if (t == 0){
    float a = fmaxf(fmaxf(lred[0],lred[1]), fmaxf(lred[2],lred[3]));
    float p = fmaxf(fmaxf(lred[4],lred[5]), fmaxf(lred[6],lred[7]));
    atomicMax((int*)&red[b],    __float_as_int(a));
    atomicMax((int*)&red[32+b], __float_as_int(p));
  }
}

// pixel pass 2: deterministic partial sums of |mod_scaled|
__global__ __launch_bounds__(256) void k_magsum(
    const float* __restrict__ msr, const float* __restrict__ msi,
    const float* __restrict__ red, float* __restrict__ magpart){
  int b = blockIdx.x >> 5, chunk = blockIdx.x & 31;
  int t = threadIdx.x;
  float maxs = red[b];
  float sum = 0.f;
  #pragma unroll
  for (int i = 0; i < 8; ++i){
    int pix = chunk*2048 + i*256 + t;
    size_t o = (size_t)b*NPIX + pix;
    float r_ = msr[o], i_ = msi[o];
    float sq = r_*r_ + i_*i_;
    float as = sqrtf(sq + EPSF);
    float hs = as/(maxs + EPSF);
    float tt = hs/(as + EPSF);
    sum += sqrtf(tt*tt*sq + EPSF);
  }
  for (int off = 32; off > 0; off >>= 1) sum += __shfl_down(sum, off);
  __shared__ float lr[4];
  int wid = t >> 6, lane = t & 63;
  if (lane == 0) lr[wid] = sum;
  __syncthreads();
  if (t == 0) magpart[b*32 + chunk] = (lr[0]+lr[1])+(lr[2]+lr[3]);
}

// final combine; folds the per-batch mag finalize
__global__ __launch_bounds__(256) void k_final(
    const float* __restrict__ msr, const float* __restrict__ msi,
    const float* __restrict__ ppr, const float* __restrict__ ppi,
    const float* __restrict__ wstat, const float* __restrict__ red,
    const float* __restrict__ magpart, float* __restrict__ out){
  int g = blockIdx.x*256 + threadIdx.x;
  int b = g >> 16, pix = g & (NPIX-1);
  __shared__ float s_im;
  if (threadIdx.x < 32){
    float v = magpart[b*32 + threadIdx.x];
    for (int off = 16; off > 0; off >>= 1) v += __shfl_down(v, off);
    if (threadIdx.x == 0) s_im = rsqrtf(v*(1.0f/65536.0f) + EPSF);
  }
  __syncthreads();
  float im = s_im;
  size_t o = (size_t)b*NPIX + pix;
  float maxs = red[b], maxp = red[32+b];
  float r_ = msr[o], i_ = msi[o], p_ = ppr[o], q_ = ppi[o];
  float as = sqrtf(r_*r_ + i_*i_ + EPSF);
  float fs = (as/(maxs+EPSF))/(as+EPSF)*im;
  float2 A0 = *(const float2*)(wstat + (size_t)pix*2);
  float mwr = A0.x + fs*r_;
  float mwi = A0.y + fs*i_;
  float ap = sqrtf(p_*p_ + q_*q_ + EPSF);
  float fp = (ap/(maxp+EPSF))/(ap+EPSF);
  float mpr = fp*p_, mpi = fp*q_;
  float den = sqrtf(mpr*mpr + mpi*mpi + EPSF);
  out[o] = (mwr*mpr + mwi*mpi)/den;
}

// ---------- launch ----------

extern "C" void kernel_launch(void* const* d_in, const int* in_sizes, int n_in,
                              void* d_out, int out_size, void* d_ws, size_t ws_size,
                              hipStream_t stream){
  const float* x     = (const float*)d_in[0];
  const float* Win   = (const float*)d_in[1];
  const float* bin   = (const float*)d_in[2];
  const float* Wg    = (const float*)d_in[3];
  const float* bg    = (const float*)d_in[4];
  const float* Wt    = (const float*)d_in[5];
  const float* bt    = (const float*)d_in[6];
  const float* convw = (const float*)d_in[7];
  const float* convb = (const float*)d_in[8];
  const float* wstat = (const float*)d_in[9];
  const float* wmod  = (const float*)d_in[10];
  float* out = (float*)d_out;
  float* ws  = (float*)d_ws;

  // layout (floats); aliases are lifetime-disjoint:
  float* xtT   = ws;                       // [FF][B], dead after normgate
  float* xgT   = ws + 262144;              //          dead after normgate
  unsigned short* ch = (unsigned short*)(ws + 524288);   // ctx hi [B][FF] bf16
  unsigned short* cm = (unsigned short*)(ws + 655360);   // ctx mid
  unsigned short* cl = (unsigned short*)(ws + 786432);   // ctx lo
  unsigned short* xh = (unsigned short*)(ws + 917504);   // x hi [B][CTX]
  unsigned short* xm = (unsigned short*)(ws + 933888);
  unsigned short* xl = (unsigned short*)(ws + 950272);
  float* ctx2T = ws;                       // alias xtT (dead by then)
  float* modc  = ws + 262144;              // alias xgT
  float* msr   = ws + 966656;              // [B][NPIX] x4 planes
  float* msi   = ws + 3063808;
  float* ppr   = ws + 5160960;
  float* ppi   = ws + 7258112;
  float* red     = ws + 9355264;           // max_s[32], max_p[32]
  float* magpart = ws + 9355328;           // [32][32]

  float* Cp1 = ppr;   // [2][4][FF][32] = 2M floats (ppr+ppi dead until pixel1)
  float* Cp2 = msr;   // [8][FF][32]    = 2M floats (msr+msi dead until pixel1)

  k_prep<<<32, 256, 0, stream>>>(x, xh, xm, xl, red);
  // GEMM1: K=1024, KSPLIT=4 (KCHUNKS=8), both weight matrices
  k_gemm_mfma<8><<<dim3(128,4,2), 256, 0, stream>>>(Win, Wg, xh, xm, xl,
                                                    Cp1, CTXD, 4ull*FFD*32);
  k_reduce1<<<2048, 256, 0, stream>>>(Cp1, bin, bg, xtT, xgT);
  k_normgate<<<128, 256, 0, stream>>>(xtT, xgT, ch, cm, cl);
  // GEMM2: K=8192, KSPLIT=8 (KCHUNKS=32)
  k_gemm_mfma<32><<<dim3(128,8,1), 256, 0, stream>>>(Wt, Wt, ch, cm, cl,
                                                     Cp2, FFD, 0);
  k_reduce2<<<1024, 256, 0, stream>>>(Cp2, bt, ctx2T);
  k_norm512<<<512, 256, 0, stream>>>(ctx2T, modc);
  k_pixel1<<<512, 256, 0, stream>>>(modc, convw, convb, wmod, wstat,
                                    msr, msi, ppr, ppi, red);
  k_magsum<<<1024, 256, 0, stream>>>(msr, msi, red, magpart);
  k_final<<<8192, 256, 0, stream>>>(msr, msi, ppr, ppi, wstat, red, magpart, out);
}

// Round 7
// 175.868 us; speedup vs baseline: 1.9587x; 1.3040x over previous
//
#include <hip/hip_runtime.h>
#include <cstddef>

#define NB   32
#define CTXD 1024
#define FFD  8192
#define HD   256
#define WD   256
#define NPIX 65536
#define EPSF 1e-12f

typedef __attribute__((ext_vector_type(8))) short bf16x8;
typedef __attribute__((ext_vector_type(4))) float f32x4;

// ---------- helpers ----------

__device__ __forceinline__ float ftanh(float x){
  float ax = fabsf(x);
  float e  = __expf(2.0f*ax);
  float r  = 1.0f - 2.0f*__builtin_amdgcn_rcpf(e + 1.0f);
  return copysignf(r, x);
}

__device__ __forceinline__ unsigned short f2bf(float f){
  unsigned u = __float_as_uint(f);
  unsigned r = (u + 0x7FFFu + ((u >> 16) & 1u)) >> 16;   // RTNE
  return (unsigned short)r;
}
__device__ __forceinline__ float bf2f(unsigned short s){
  return __uint_as_float((unsigned)s << 16);
}

// split f32 -> 3 bf16 terms (residual ~2^-27 relative)
__device__ __forceinline__ void split3(float f, unsigned short& s0,
                                       unsigned short& s1, unsigned short& s2){
  s0 = f2bf(f);
  float r1 = f - bf2f(s0);
  s1 = f2bf(r1);
  float r2 = r1 - bf2f(s1);
  s2 = f2bf(r2);
}

__device__ __forceinline__ void block_reduce4(float& a, float& b, float& c, float& d){
  for (int off = 32; off > 0; off >>= 1){
    a += __shfl_down(a, off); b += __shfl_down(b, off);
    c += __shfl_down(c, off); d += __shfl_down(d, off);
  }
  __shared__ float lds[16];
  int wid = threadIdx.x >> 6, lane = threadIdx.x & 63;
  if (lane == 0){ lds[wid*4+0]=a; lds[wid*4+1]=b; lds[wid*4+2]=c; lds[wid*4+3]=d; }
  __syncthreads();
  a = (lds[0]+lds[4])+(lds[8]+lds[12]);
  b = (lds[1]+lds[5])+(lds[9]+lds[13]);
  c = (lds[2]+lds[6])+(lds[10]+lds[14]);
  d = (lds[3]+lds[7])+(lds[11]+lds[15]);
}

// ---------- kernels ----------

// split x [32][1024] f32 -> packed B-fragment layout, zero red[]
// pack: [chunk][plane][half][kg][col16][8k] shorts; chunk stride 3072 shorts
__global__ __launch_bounds__(256) void k_prep(
    const float* __restrict__ x, unsigned short* __restrict__ P,
    float* __restrict__ red){
  int g = blockIdx.x*256 + threadIdx.x;      // 4096 = 32 rows x 128 groups
  if (g < 64) red[g] = 0.0f;
  int b = g >> 7, grp = g & 127;
  int koff = grp*8;
  int c = grp >> 2, kg = grp & 3;
  const float* src = x + (size_t)b*CTXD + koff;
  float4 v0 = *(const float4*)(src), v1 = *(const float4*)(src+4);
  float vv[8] = {v0.x,v0.y,v0.z,v0.w,v1.x,v1.y,v1.z,v1.w};
  bf16x8 a0, a1, a2;
  #pragma unroll
  for (int e = 0; e < 8; ++e){
    unsigned short s0,s1,s2; split3(vv[e],s0,s1,s2);
    a0[e]=(short)s0; a1[e]=(short)s1; a2[e]=(short)s2;
  }
  size_t base = (size_t)c*3072 + (b>>4)*512 + kg*128 + (b&15)*8;
  *(bf16x8*)(P + base)        = a0;
  *(bf16x8*)(P + base + 1024) = a1;
  *(bf16x8*)(P + base + 2048) = a2;
}

// Split-bf16 MFMA GEMM (f32-accurate): Cp[z][kc][f][b] = sum_k W[f][k]*ctx[b][k].
// W streamed f32, split to 3 bf16 in-register; ctx pre-packed fragment-ready.
// Per-block k-rotation kills the L2-channel hotspot of the 32KB row stride.
template<int KC>
__global__ __launch_bounds__(256) void k_gemm_mfma(
    const float* __restrict__ W0, const float* __restrict__ W1,
    const unsigned short* __restrict__ BP,
    float* __restrict__ Cp, int K, size_t zstride){
  const float* __restrict__ W = blockIdx.z ? W1 : W0;
  int wave = threadIdx.x >> 6;
  int lane = threadIdx.x & 63;
  int f0   = blockIdx.x*64 + wave*16;
  int kc   = blockIdx.y;
  int row  = lane & 15;
  int kg   = lane >> 4;
  int rot  = blockIdx.x & (KC-1);
  const float* Wb = W + (size_t)(f0+row)*K + kc*KC*32 + kg*8;
  const unsigned short* Bb = BP + (size_t)kc*KC*3072 + kg*128 + row*8;
  f32x4 acc0={0.f,0.f,0.f,0.f}, acc1={0.f,0.f,0.f,0.f};
  // prefetch W chunk 0 (HBM stream; B comes from L2 per-iteration)
  const float* wp = Wb + rot*32;
  float4 w0 = *(const float4*)(wp), w1 = *(const float4*)(wp+4);
  for (int c = 0; c < KC; ++c){
    int rc = (c + rot) & (KC-1);
    // B loads first (L2-hot; latency hides under split3 VALU)
    const unsigned short* bp = Bb + (size_t)rc*3072;
    bf16x8 b0h0 = *(const bf16x8*)(bp);
    bf16x8 b0h1 = *(const bf16x8*)(bp +  512);
    bf16x8 b1h0 = *(const bf16x8*)(bp + 1024);
    bf16x8 b1h1 = *(const bf16x8*)(bp + 1536);
    bf16x8 b2h0 = *(const bf16x8*)(bp + 2048);
    bf16x8 b2h1 = *(const bf16x8*)(bp + 2560);
    float4 cw0 = w0, cw1 = w1;
    if (c + 1 < KC){                     // issue next W after B so waiting on B
      int rn = (c + 1 + rot) & (KC-1);   // doesn't drain the W prefetch
      wp = Wb + rn*32;
      w0 = *(const float4*)(wp); w1 = *(const float4*)(wp+4);
    }
    bf16x8 a0, a1, a2;
    float wv[8] = {cw0.x,cw0.y,cw0.z,cw0.w,cw1.x,cw1.y,cw1.z,cw1.w};
    #pragma unroll
    for (int e = 0; e < 8; ++e){
      unsigned short s0,s1,s2; split3(wv[e],s0,s1,s2);
      a0[e]=(short)s0; a1[e]=(short)s1; a2[e]=(short)s2;
    }
    acc0 = __builtin_amdgcn_mfma_f32_16x16x32_bf16(a0, b0h0, acc0, 0,0,0);
    acc1 = __builtin_amdgcn_mfma_f32_16x16x32_bf16(a0, b0h1, acc1, 0,0,0);
    acc0 = __builtin_amdgcn_mfma_f32_16x16x32_bf16(a0, b1h0, acc0, 0,0,0);
    acc1 = __builtin_amdgcn_mfma_f32_16x16x32_bf16(a0, b1h1, acc1, 0,0,0);
    acc0 = __builtin_amdgcn_mfma_f32_16x16x32_bf16(a1, b0h0, acc0, 0,0,0);
    acc1 = __builtin_amdgcn_mfma_f32_16x16x32_bf16(a1, b0h1, acc1, 0,0,0);
    acc0 = __builtin_amdgcn_mfma_f32_16x16x32_bf16(a0, b2h0, acc0, 0,0,0);
    acc1 = __builtin_amdgcn_mfma_f32_16x16x32_bf16(a0, b2h1, acc1, 0,0,0);
    acc0 = __builtin_amdgcn_mfma_f32_16x16x32_bf16(a1, b1h0, acc0, 0,0,0);
    acc1 = __builtin_amdgcn_mfma_f32_16x16x32_bf16(a1, b1h1, acc1, 0,0,0);
    acc0 = __builtin_amdgcn_mfma_f32_16x16x32_bf16(a2, b0h0, acc0, 0,0,0);
    acc1 = __builtin_amdgcn_mfma_f32_16x16x32_bf16(a2, b0h1, acc1, 0,0,0);
  }
  float* __restrict__ C = Cp + (size_t)blockIdx.z*zstride + (size_t)kc*(FFD*32);
  #pragma unroll
  for (int r = 0; r < 4; ++r){          // C/D: col=lane&15, row=kg*4+r
    int f = f0 + kg*4 + r;
    C[(size_t)f*32 + row]      = acc0[r];
    C[(size_t)f*32 + 16 + row] = acc1[r];
  }
}

// reduce for GEMM1 (both matrices), S=8
__global__ __launch_bounds__(256) void k_reduce1(
    const float* __restrict__ Cp, const float* __restrict__ bin,
    const float* __restrict__ bg, float* __restrict__ xtT,
    float* __restrict__ xgT){
  int g = blockIdx.x*256 + threadIdx.x;          // 524288
  int m = g >> 18, idx = g & 262143;
  int f = idx >> 5;
  const float* __restrict__ cp = Cp + (size_t)m*(8ull*FFD*32);
  float s = (m ? bg : bin)[f];
  #pragma unroll
  for (int sI = 0; sI < 8; ++sI) s += cp[(size_t)sI*(FFD*32) + idx];
  (m ? xgT : xtT)[idx] = s;
}

// reduce for GEMM2, S=16
__global__ __launch_bounds__(256) void k_reduce2(
    const float* __restrict__ Cp, const float* __restrict__ bias,
    float* __restrict__ outT){
  int g = blockIdx.x*256 + threadIdx.x;          // 262144
  int f = g >> 5;
  float s = bias[f];
  #pragma unroll
  for (int sI = 0; sI < 16; ++sI) s += Cp[(size_t)sI*(FFD*32) + g];
  outT[g] = s;
}

// norm over 2048-groups (ddof=1); ctx = nt*tanh(ng) -> packed B-fragment layout
__global__ __launch_bounds__(256) void k_normgate(
    const float* __restrict__ xtT, const float* __restrict__ xgT,
    unsigned short* __restrict__ P){
  int b = blockIdx.x >> 2, g4 = blockIdx.x & 3;
  int t = threadIdx.x;
  int f8 = g4*2048 + t*8;                // 8 consecutive f per thread
  float vt[8], vg[8];
  float st=0.f, sst=0.f, sg=0.f, ssg=0.f;
  #pragma unroll
  for (int i = 0; i < 8; ++i){
    int f = f8 + i;
    float a = xtT[(size_t)f*NB + b];
    float c = xgT[(size_t)f*NB + b];
    vt[i]=a; vg[i]=c;
    st += a; sst += a*a; sg += c; ssg += c*c;
  }
  block_reduce4(st, sst, sg, ssg);
  float mt = st * (1.0f/2048.0f);
  float it = rsqrtf((sst - st*mt) * (1.0f/2047.0f) + EPSF);
  float mg = sg * (1.0f/2048.0f);
  float ig = rsqrtf((ssg - sg*mg) * (1.0f/2047.0f) + EPSF);
  bf16x8 a0, a1, a2;
  #pragma unroll
  for (int i = 0; i < 8; ++i){
    float nt = (vt[i]-mt)*it;
    float ng = (vg[i]-mg)*ig;
    float cv = nt * ftanh(ng);
    unsigned short s0,s1,s2; split3(cv,s0,s1,s2);
    a0[i]=(short)s0; a1[i]=(short)s1; a2[i]=(short)s2;
  }
  int c2 = f8 >> 5, kg = (f8 >> 3) & 3;
  size_t base = (size_t)c2*3072 + (b>>4)*512 + kg*128 + (b&15)*8;
  *(bf16x8*)(P + base)        = a0;
  *(bf16x8*)(P + base + 1024) = a1;
  *(bf16x8*)(P + base + 2048) = a2;
}

// norm over 512-groups (ddof=1) -> modc [B][16][512]
__global__ __launch_bounds__(256) void k_norm512(
    const float* __restrict__ ctx2T, float* __restrict__ modc){
  int b = blockIdx.x >> 4, kr = blockIdx.x & 15;
  int t = threadIdx.x;
  int base = kr*512;
  float v0 = ctx2T[(base + t      )*NB + b];
  float v1 = ctx2T[(base + 256 + t)*NB + b];
  float s = v0+v1, ss = v0*v0 + v1*v1, d0=0.f, d1=0.f;
  block_reduce4(s, ss, d0, d1);
  float m   = s * (1.0f/512.0f);
  float inv = rsqrtf((ss - s*m) * (1.0f/511.0f) + EPSF);
  modc[b*FFD + base + t      ] = (v0-m)*inv;
  modc[b*FFD + base + 256 + t] = (v1-m)*inv;
}

// pixel pass 1: tanh outer products, channel mix, store planes + per-batch max
__global__ __launch_bounds__(256) void k_pixel1(
    const float* __restrict__ modc,
    const float* __restrict__ convw, const float* __restrict__ convb,
    const float* __restrict__ wmod, const float* __restrict__ wstat,
    float* __restrict__ msr, float* __restrict__ msi,
    float* __restrict__ ppr, float* __restrict__ ppi,
    float* __restrict__ red){
  int b = blockIdx.x >> 4, chunk = blockIdx.x & 15;
  int t = threadIdx.x;
  __shared__ float lds[16*512];
  #pragma unroll
  for (int i = 0; i < 8; ++i){
    float4 v = *(const float4*)(modc + (size_t)b*FFD + (i*256 + t)*4);
    *(float4*)(lds + (i*256 + t)*4) = v;
  }
  float cw0 = convw[0]+convw[4]+convw[8]+convw[12];
  float cw1 = convw[1]+convw[5]+convw[9]+convw[13];
  float cw2 = convw[2]+convw[6]+convw[10]+convw[14];
  float cw3 = convw[3]+convw[7]+convw[11]+convw[15];
  float cb  = convb[0]+convb[1]+convb[2]+convb[3];
  __syncthreads();
  int w = t;
  float mxs = 0.f, mxp = 0.f;
  for (int it = 0; it < 16; ++it){
    int h = chunk*16 + it;
    int pix = h*WD + w;
    float sk[4];
    #pragma unroll
    for (int k = 0; k < 4; ++k){
      float acc = 0.f;
      #pragma unroll
      for (int r = 0; r < 4; ++r){
        int kr = k*4 + r;
        float u  = lds[kr*512 + h];
        float vv = lds[kr*512 + 256 + w];
        float tt = ftanh(u*vv);
        float cwr = (r==0)?cw0:(r==1)?cw1:(r==2)?cw2:cw3;
        acc += (k==0) ? cwr*tt : tt;
      }
      sk[k] = acc;
    }
    sk[0] += cb;
    float m0 = sk[0]*wmod[0*NPIX+pix];
    float m1 = sk[1]*wmod[1*NPIX+pix];
    float m2 = sk[2]*wmod[2*NPIX+pix];
    float m3 = sk[3]*wmod[3*NPIX+pix];
    float2 A1 = *(const float2*)(wstat + (size_t)(NPIX + pix)*2);
    float r_ = A1.x*m0 - A1.y*m1;
    float i_ = A1.x*m1 - A1.y*m0;
    size_t o = (size_t)b*NPIX + pix;
    msr[o]=r_; msi[o]=i_; ppr[o]=m2; ppi[o]=m3;
    float as = sqrtf(r_*r_ + i_*i_ + EPSF);
    float ap = sqrtf(m2*m2 + m3*m3 + EPSF);
    mxs = fmaxf(mxs, as); mxp = fmaxf(mxp, ap);
  }
  for (int off = 32; off > 0; off >>= 1){
    mxs = fmaxf(mxs, __shfl_down(mxs, off));
    mxp = fmaxf(mxp, __shfl_down(mxp, off));
  }
  __shared__ float lred[8];
  int wid = t >> 6, lane = t & 63;
  if (lane == 0){ lred[wid] = mxs; lred[4+wid] = mxp; }
  __syncthreads();
  if (t == 0){
    float a = fmaxf(fmaxf(lred[0],lred[1]), fmaxf(lred[2],lred[3]));
    float p = fmaxf(fmaxf(lred[4],lred[5]), fmaxf(lred[6],lred[7]));
    atomicMax((int*)&red[b],    __float_as_int(a));
    atomicMax((int*)&red[32+b], __float_as_int(p));
  }
}

// pixel pass 2: deterministic partial sums of |mod_scaled|
__global__ __launch_bounds__(256) void k_magsum(
    const float* __restrict__ msr, const float* __restrict__ msi,
    const float* __restrict__ red, float* __restrict__ magpart){
  int b = blockIdx.x >> 5, chunk = blockIdx.x & 31;
  int t = threadIdx.x;
  float maxs = red[b];
  float sum = 0.f;
  #pragma unroll
  for (int i = 0; i < 8; ++i){
    int pix = chunk*2048 + i*256 + t;
    size_t o = (size_t)b*NPIX + pix;
    float r_ = msr[o], i_ = msi[o];
    float sq = r_*r_ + i_*i_;
    float as = sqrtf(sq + EPSF);
    float hs = as/(maxs + EPSF);
    float tt = hs/(as + EPSF);
    sum += sqrtf(tt*tt*sq + EPSF);
  }
  for (int off = 32; off > 0; off >>= 1) sum += __shfl_down(sum, off);
  __shared__ float lr[4];
  int wid = t >> 6, lane = t & 63;
  if (lane == 0) lr[wid] = sum;
  __syncthreads();
  if (t == 0) magpart[b*32 + chunk] = (lr[0]+lr[1])+(lr[2]+lr[3]);
}

// final combine; folds the per-batch mag finalize
__global__ __launch_bounds__(256) void k_final(
    const float* __restrict__ msr, const float* __restrict__ msi,
    const float* __restrict__ ppr, const float* __restrict__ ppi,
    const float* __restrict__ wstat, const float* __restrict__ red,
    const float* __restrict__ magpart, float* __restrict__ out){
  int g = blockIdx.x*256 + threadIdx.x;
  int b = g >> 16, pix = g & (NPIX-1);
  __shared__ float s_im;
  if (threadIdx.x < 32){
    float v = magpart[b*32 + threadIdx.x];
    for (int off = 16; off > 0; off >>= 1) v += __shfl_down(v, off);
    if (threadIdx.x == 0) s_im = rsqrtf(v*(1.0f/65536.0f) + EPSF);
  }
  __syncthreads();
  float im = s_im;
  size_t o = (size_t)b*NPIX + pix;
  float maxs = red[b], maxp = red[32+b];
  float r_ = msr[o], i_ = msi[o], p_ = ppr[o], q_ = ppi[o];
  float as = sqrtf(r_*r_ + i_*i_ + EPSF);
  float fs = (as/(maxs+EPSF))/(as+EPSF)*im;
  float2 A0 = *(const float2*)(wstat + (size_t)pix*2);
  float mwr = A0.x + fs*r_;
  float mwi = A0.y + fs*i_;
  float ap = sqrtf(p_*p_ + q_*q_ + EPSF);
  float fp = (ap/(maxp+EPSF))/(ap+EPSF);
  float mpr = fp*p_, mpi = fp*q_;
  float den = sqrtf(mpr*mpr + mpi*mpi + EPSF);
  out[o] = (mwr*mpr + mwi*mpi)/den;
}

// ---------- launch ----------

extern "C" void kernel_launch(void* const* d_in, const int* in_sizes, int n_in,
                              void* d_out, int out_size, void* d_ws, size_t ws_size,
                              hipStream_t stream){
  const float* x     = (const float*)d_in[0];
  const float* Win   = (const float*)d_in[1];
  const float* bin   = (const float*)d_in[2];
  const float* Wg    = (const float*)d_in[3];
  const float* bg    = (const float*)d_in[4];
  const float* Wt    = (const float*)d_in[5];
  const float* bt    = (const float*)d_in[6];
  const float* convw = (const float*)d_in[7];
  const float* convb = (const float*)d_in[8];
  const float* wstat = (const float*)d_in[9];
  const float* wmod  = (const float*)d_in[10];
  float* out = (float*)d_out;
  float* ws  = (float*)d_ws;

  // layout (floats); aliases are lifetime-disjoint:
  float* xtT   = ws;                       // [FF][B], dead after normgate
  float* xgT   = ws + 262144;              //          dead after normgate
  unsigned short* P2 = (unsigned short*)(ws + 524288);   // ctx pack, 256 chunks
  unsigned short* P1 = (unsigned short*)(ws + 917504);   // x pack, 32 chunks
  float* ctx2T = ws;                       // alias xtT (dead by then)
  float* modc  = ws + 262144;              // alias xgT
  float* msr   = ws + 966656;              // [B][NPIX] x4 planes
  float* msi   = ws + 3063808;
  float* ppr   = ws + 5160960;
  float* ppi   = ws + 7258112;
  float* red     = ws + 9355264;           // max_s[32], max_p[32]
  float* magpart = ws + 9355328;           // [32][32]

  float* Cp2 = msr;   // [16][FF][32] = 4M floats (msr+msi dead until pixel1)
  float* Cp1 = ppr;   // [2][8][FF][32] = 4M floats (ppr+ppi dead until pixel1)

  k_prep<<<16, 256, 0, stream>>>(x, P1, red);
  // GEMM1: K=1024, KSPLIT=8 (KC=4), both weight matrices
  k_gemm_mfma<4><<<dim3(128,8,2), 256, 0, stream>>>(Win, Wg, P1,
                                                    Cp1, CTXD, 8ull*FFD*32);
  k_reduce1<<<2048, 256, 0, stream>>>(Cp1, bin, bg, xtT, xgT);
  k_normgate<<<128, 256, 0, stream>>>(xtT, xgT, P2);
  // GEMM2: K=8192, KSPLIT=16 (KC=16)
  k_gemm_mfma<16><<<dim3(128,16,1), 256, 0, stream>>>(Wt, Wt, P2,
                                                      Cp2, FFD, 0);
  k_reduce2<<<1024, 256, 0, stream>>>(Cp2, bt, ctx2T);
  k_norm512<<<512, 256, 0, stream>>>(ctx2T, modc);
  k_pixel1<<<512, 256, 0, stream>>>(modc, convw, convb, wmod, wstat,
                                    msr, msi, ppr, ppi, red);
  k_magsum<<<1024, 256, 0, stream>>>(msr, msi, red, magpart);
  k_final<<<8192, 256, 0, stream>>>(msr, msi, ppr, ppi, wstat, red, magpart, out);
}

// Round 8
// 174.012 us; speedup vs baseline: 1.9795x; 1.0107x over previous
//
#include <hip/hip_runtime.h>
#include <cstddef>

#define NB   32
#define CTXD 1024
#define FFD  8192
#define HD   256
#define WD   256
#define NPIX 65536
#define EPSF 1e-12f

typedef __attribute__((ext_vector_type(8))) short bf16x8;
typedef __attribute__((ext_vector_type(4))) float f32x4;

// ---------- helpers ----------

__device__ __forceinline__ float ftanh(float x){
  float ax = fabsf(x);
  float e  = __expf(2.0f*ax);
  float r  = 1.0f - 2.0f*__builtin_amdgcn_rcpf(e + 1.0f);
  return copysignf(r, x);
}

__device__ __forceinline__ unsigned short f2bf(float f){
  unsigned u = __float_as_uint(f);
  unsigned r = (u + 0x7FFFu + ((u >> 16) & 1u)) >> 16;   // RTNE
  return (unsigned short)r;
}
__device__ __forceinline__ float bf2f(unsigned short s){
  return __uint_as_float((unsigned)s << 16);
}

// split f32 -> 3 bf16 terms (residual ~2^-27 relative)
__device__ __forceinline__ void split3(float f, unsigned short& s0,
                                       unsigned short& s1, unsigned short& s2){
  s0 = f2bf(f);
  float r1 = f - bf2f(s0);
  s1 = f2bf(r1);
  float r2 = r1 - bf2f(s1);
  s2 = f2bf(r2);
}

__device__ __forceinline__ void block_reduce4(float& a, float& b, float& c, float& d){
  for (int off = 32; off > 0; off >>= 1){
    a += __shfl_down(a, off); b += __shfl_down(b, off);
    c += __shfl_down(c, off); d += __shfl_down(d, off);
  }
  __shared__ float lds[16];
  int wid = threadIdx.x >> 6, lane = threadIdx.x & 63;
  if (lane == 0){ lds[wid*4+0]=a; lds[wid*4+1]=b; lds[wid*4+2]=c; lds[wid*4+3]=d; }
  __syncthreads();
  a = (lds[0]+lds[4])+(lds[8]+lds[12]);
  b = (lds[1]+lds[5])+(lds[9]+lds[13]);
  c = (lds[2]+lds[6])+(lds[10]+lds[14]);
  d = (lds[3]+lds[7])+(lds[11]+lds[15]);
}

// per-pixel recompute core shared by k_scan / k_final (must stay identical)
__device__ __forceinline__ void pixel_core(
    const float* __restrict__ lds, int h, int w, int pix,
    float cw0, float cw1, float cw2, float cw3, float cb,
    const float* __restrict__ wmod, const float* __restrict__ wstat,
    float& r_, float& i_, float& p_, float& q_){
  float sk[4];
  #pragma unroll
  for (int k = 0; k < 4; ++k){
    float acc = 0.f;
    #pragma unroll
    for (int r = 0; r < 4; ++r){
      int kr = k*4 + r;
      float u  = lds[kr*512 + h];
      float vv = lds[kr*512 + 256 + w];
      float tt = ftanh(u*vv);
      float cwr = (r==0)?cw0:(r==1)?cw1:(r==2)?cw2:cw3;
      acc += (k==0) ? cwr*tt : tt;
    }
    sk[k] = acc;
  }
  sk[0] += cb;
  float m0 = sk[0]*wmod[0*NPIX+pix];
  float m1 = sk[1]*wmod[1*NPIX+pix];
  float m2 = sk[2]*wmod[2*NPIX+pix];
  float m3 = sk[3]*wmod[3*NPIX+pix];
  float2 A1 = *(const float2*)(wstat + (size_t)(NPIX + pix)*2);
  r_ = A1.x*m0 - A1.y*m1;
  i_ = A1.x*m1 - A1.y*m0;
  p_ = m2; q_ = m3;
}

// ---------- kernels ----------

// split x [32][1024] f32 -> packed B-fragment layout, zero red[]
__global__ __launch_bounds__(256) void k_prep(
    const float* __restrict__ x, unsigned short* __restrict__ P,
    float* __restrict__ red){
  int g = blockIdx.x*256 + threadIdx.x;      // 4096 = 32 rows x 128 groups
  if (g < 64) red[g] = 0.0f;
  int b = g >> 7, grp = g & 127;
  int koff = grp*8;
  int c = grp >> 2, kg = grp & 3;
  const float* src = x + (size_t)b*CTXD + koff;
  float4 v0 = *(const float4*)(src), v1 = *(const float4*)(src+4);
  float vv[8] = {v0.x,v0.y,v0.z,v0.w,v1.x,v1.y,v1.z,v1.w};
  bf16x8 a0, a1, a2;
  #pragma unroll
  for (int e = 0; e < 8; ++e){
    unsigned short s0,s1,s2; split3(vv[e],s0,s1,s2);
    a0[e]=(short)s0; a1[e]=(short)s1; a2[e]=(short)s2;
  }
  size_t base = (size_t)c*3072 + (b>>4)*512 + kg*128 + (b&15)*8;
  *(bf16x8*)(P + base)        = a0;
  *(bf16x8*)(P + base + 1024) = a1;
  *(bf16x8*)(P + base + 2048) = a2;
}

// Split-bf16 MFMA GEMM (f32-accurate): Cp[z][kc][f][b] = sum_k W[f][k]*ctx[b][k].
template<int KC>
__global__ __launch_bounds__(256) void k_gemm_mfma(
    const float* __restrict__ W0, const float* __restrict__ W1,
    const unsigned short* __restrict__ BP,
    float* __restrict__ Cp, int K, size_t zstride){
  const float* __restrict__ W = blockIdx.z ? W1 : W0;
  int wave = threadIdx.x >> 6;
  int lane = threadIdx.x & 63;
  int f0   = blockIdx.x*64 + wave*16;
  int kc   = blockIdx.y;
  int row  = lane & 15;
  int kg   = lane >> 4;
  int rot  = blockIdx.x & (KC-1);
  const float* Wb = W + (size_t)(f0+row)*K + kc*KC*32 + kg*8;
  const unsigned short* Bb = BP + (size_t)kc*KC*3072 + kg*128 + row*8;
  f32x4 acc0={0.f,0.f,0.f,0.f}, acc1={0.f,0.f,0.f,0.f};
  const float* wp = Wb + rot*32;
  float4 w0 = *(const float4*)(wp), w1 = *(const float4*)(wp+4);
  for (int c = 0; c < KC; ++c){
    int rc = (c + rot) & (KC-1);
    const unsigned short* bp = Bb + (size_t)rc*3072;
    bf16x8 b0h0 = *(const bf16x8*)(bp);
    bf16x8 b0h1 = *(const bf16x8*)(bp +  512);
    bf16x8 b1h0 = *(const bf16x8*)(bp + 1024);
    bf16x8 b1h1 = *(const bf16x8*)(bp + 1536);
    bf16x8 b2h0 = *(const bf16x8*)(bp + 2048);
    bf16x8 b2h1 = *(const bf16x8*)(bp + 2560);
    float4 cw0 = w0, cw1 = w1;
    if (c + 1 < KC){
      int rn = (c + 1 + rot) & (KC-1);
      wp = Wb + rn*32;
      w0 = *(const float4*)(wp); w1 = *(const float4*)(wp+4);
    }
    bf16x8 a0, a1, a2;
    float wv[8] = {cw0.x,cw0.y,cw0.z,cw0.w,cw1.x,cw1.y,cw1.z,cw1.w};
    #pragma unroll
    for (int e = 0; e < 8; ++e){
      unsigned short s0,s1,s2; split3(wv[e],s0,s1,s2);
      a0[e]=(short)s0; a1[e]=(short)s1; a2[e]=(short)s2;
    }
    acc0 = __builtin_amdgcn_mfma_f32_16x16x32_bf16(a0, b0h0, acc0, 0,0,0);
    acc1 = __builtin_amdgcn_mfma_f32_16x16x32_bf16(a0, b0h1, acc1, 0,0,0);
    acc0 = __builtin_amdgcn_mfma_f32_16x16x32_bf16(a0, b1h0, acc0, 0,0,0);
    acc1 = __builtin_amdgcn_mfma_f32_16x16x32_bf16(a0, b1h1, acc1, 0,0,0);
    acc0 = __builtin_amdgcn_mfma_f32_16x16x32_bf16(a1, b0h0, acc0, 0,0,0);
    acc1 = __builtin_amdgcn_mfma_f32_16x16x32_bf16(a1, b0h1, acc1, 0,0,0);
    acc0 = __builtin_amdgcn_mfma_f32_16x16x32_bf16(a0, b2h0, acc0, 0,0,0);
    acc1 = __builtin_amdgcn_mfma_f32_16x16x32_bf16(a0, b2h1, acc1, 0,0,0);
    acc0 = __builtin_amdgcn_mfma_f32_16x16x32_bf16(a1, b1h0, acc0, 0,0,0);
    acc1 = __builtin_amdgcn_mfma_f32_16x16x32_bf16(a1, b1h1, acc1, 0,0,0);
    acc0 = __builtin_amdgcn_mfma_f32_16x16x32_bf16(a2, b0h0, acc0, 0,0,0);
    acc1 = __builtin_amdgcn_mfma_f32_16x16x32_bf16(a2, b0h1, acc1, 0,0,0);
  }
  float* __restrict__ C = Cp + (size_t)blockIdx.z*zstride + (size_t)kc*(FFD*32);
  #pragma unroll
  for (int r = 0; r < 4; ++r){
    int f = f0 + kg*4 + r;
    C[(size_t)f*32 + row]      = acc0[r];
    C[(size_t)f*32 + 16 + row] = acc1[r];
  }
}

// reduce for GEMM1 (both matrices), S=8
__global__ __launch_bounds__(256) void k_reduce1(
    const float* __restrict__ Cp, const float* __restrict__ bin,
    const float* __restrict__ bg, float* __restrict__ xtT,
    float* __restrict__ xgT){
  int g = blockIdx.x*256 + threadIdx.x;          // 524288
  int m = g >> 18, idx = g & 262143;
  int f = idx >> 5;
  const float* __restrict__ cp = Cp + (size_t)m*(8ull*FFD*32);
  float s = (m ? bg : bin)[f];
  #pragma unroll
  for (int sI = 0; sI < 8; ++sI) s += cp[(size_t)sI*(FFD*32) + idx];
  (m ? xgT : xtT)[idx] = s;
}

// reduce for GEMM2, S=16
__global__ __launch_bounds__(256) void k_reduce2(
    const float* __restrict__ Cp, const float* __restrict__ bias,
    float* __restrict__ outT){
  int g = blockIdx.x*256 + threadIdx.x;          // 262144
  int f = g >> 5;
  float s = bias[f];
  #pragma unroll
  for (int sI = 0; sI < 16; ++sI) s += Cp[(size_t)sI*(FFD*32) + g];
  outT[g] = s;
}

// norm over 2048-groups (ddof=1); ctx = nt*tanh(ng) -> packed B-fragment layout
__global__ __launch_bounds__(256) void k_normgate(
    const float* __restrict__ xtT, const float* __restrict__ xgT,
    unsigned short* __restrict__ P){
  int b = blockIdx.x >> 2, g4 = blockIdx.x & 3;
  int t = threadIdx.x;
  int f8 = g4*2048 + t*8;
  float vt[8], vg[8];
  float st=0.f, sst=0.f, sg=0.f, ssg=0.f;
  #pragma unroll
  for (int i = 0; i < 8; ++i){
    int f = f8 + i;
    float a = xtT[(size_t)f*NB + b];
    float c = xgT[(size_t)f*NB + b];
    vt[i]=a; vg[i]=c;
    st += a; sst += a*a; sg += c; ssg += c*c;
  }
  block_reduce4(st, sst, sg, ssg);
  float mt = st * (1.0f/2048.0f);
  float it = rsqrtf((sst - st*mt) * (1.0f/2047.0f) + EPSF);
  float mg = sg * (1.0f/2048.0f);
  float ig = rsqrtf((ssg - sg*mg) * (1.0f/2047.0f) + EPSF);
  bf16x8 a0, a1, a2;
  #pragma unroll
  for (int i = 0; i < 8; ++i){
    float nt = (vt[i]-mt)*it;
    float ng = (vg[i]-mg)*ig;
    float cv = nt * ftanh(ng);
    unsigned short s0,s1,s2; split3(cv,s0,s1,s2);
    a0[i]=(short)s0; a1[i]=(short)s1; a2[i]=(short)s2;
  }
  int c2 = f8 >> 5, kg = (f8 >> 3) & 3;
  size_t base = (size_t)c2*3072 + (b>>4)*512 + kg*128 + (b&15)*8;
  *(bf16x8*)(P + base)        = a0;
  *(bf16x8*)(P + base + 1024) = a1;
  *(bf16x8*)(P + base + 2048) = a2;
}

// norm over 512-groups (ddof=1) -> modc [B][16][512]
__global__ __launch_bounds__(256) void k_norm512(
    const float* __restrict__ ctx2T, float* __restrict__ modc){
  int b = blockIdx.x >> 4, kr = blockIdx.x & 15;
  int t = threadIdx.x;
  int base = kr*512;
  float v0 = ctx2T[(base + t      )*NB + b];
  float v1 = ctx2T[(base + 256 + t)*NB + b];
  float s = v0+v1, ss = v0*v0 + v1*v1, d0=0.f, d1=0.f;
  block_reduce4(s, ss, d0, d1);
  float m   = s * (1.0f/512.0f);
  float inv = rsqrtf((ss - s*m) * (1.0f/511.0f) + EPSF);
  modc[b*FFD + base + t      ] = (v0-m)*inv;
  modc[b*FFD + base + 256 + t] = (v1-m)*inv;
}

// scan pass: per-batch max_s/max_p + Sigma|v_s| partials. No plane stores.
__global__ __launch_bounds__(256) void k_scan(
    const float* __restrict__ modc,
    const float* __restrict__ convw, const float* __restrict__ convb,
    const float* __restrict__ wmod, const float* __restrict__ wstat,
    float* __restrict__ red, float* __restrict__ magpart){
  int b = blockIdx.x >> 4, chunk = blockIdx.x & 15;
  int t = threadIdx.x;
  __shared__ float lds[16*512];
  #pragma unroll
  for (int i = 0; i < 8; ++i){
    float4 v = *(const float4*)(modc + (size_t)b*FFD + (i*256 + t)*4);
    *(float4*)(lds + (i*256 + t)*4) = v;
  }
  float cw0 = convw[0]+convw[4]+convw[8]+convw[12];
  float cw1 = convw[1]+convw[5]+convw[9]+convw[13];
  float cw2 = convw[2]+convw[6]+convw[10]+convw[14];
  float cw3 = convw[3]+convw[7]+convw[11]+convw[15];
  float cb  = convb[0]+convb[1]+convb[2]+convb[3];
  __syncthreads();
  int w = t;
  float mxs = 0.f, mxp = 0.f, sas = 0.f;
  for (int it = 0; it < 16; ++it){
    int h = chunk*16 + it;
    int pix = h*WD + w;
    float r_, i_, p_, q_;
    pixel_core(lds, h, w, pix, cw0, cw1, cw2, cw3, cb, wmod, wstat,
               r_, i_, p_, q_);
    float as = sqrtf(r_*r_ + i_*i_ + EPSF);
    float ap = sqrtf(p_*p_ + q_*q_ + EPSF);
    mxs = fmaxf(mxs, as); mxp = fmaxf(mxp, ap);
    sas += as;
  }
  for (int off = 32; off > 0; off >>= 1){
    mxs = fmaxf(mxs, __shfl_down(mxs, off));
    mxp = fmaxf(mxp, __shfl_down(mxp, off));
    sas += __shfl_down(sas, off);
  }
  __shared__ float lred[12];
  int wid = t >> 6, lane = t & 63;
  if (lane == 0){ lred[wid] = mxs; lred[4+wid] = mxp; lred[8+wid] = sas; }
  __syncthreads();
  if (t == 0){
    float a = fmaxf(fmaxf(lred[0],lred[1]), fmaxf(lred[2],lred[3]));
    float p = fmaxf(fmaxf(lred[4],lred[5]), fmaxf(lred[6],lred[7]));
    float s = (lred[8]+lred[9])+(lred[10]+lred[11]);
    atomicMax((int*)&red[b],    __float_as_int(a));
    atomicMax((int*)&red[32+b], __float_as_int(p));
    magpart[b*16 + chunk] = s;
  }
}

// final: recompute pixels, combine with per-batch stats -> out
__global__ __launch_bounds__(256) void k_final(
    const float* __restrict__ modc,
    const float* __restrict__ convw, const float* __restrict__ convb,
    const float* __restrict__ wmod, const float* __restrict__ wstat,
    const float* __restrict__ red, const float* __restrict__ magpart,
    float* __restrict__ out){
  int b = blockIdx.x >> 4, chunk = blockIdx.x & 15;
  int t = threadIdx.x;
  __shared__ float lds[16*512];
  __shared__ float s_im;
  if (t < 16){
    float v = magpart[b*16 + t];
    for (int off = 8; off > 0; off >>= 1) v += __shfl_down(v, off);
    if (t == 0){
      float maxs = red[b];
      // mean|mod_scaled| ~= (Sigma as)/(N*(maxs+eps)); error ~1e-6 absolute
      s_im = rsqrtf(v*(1.0f/65536.0f)/(maxs + EPSF) + EPSF);
    }
  }
  #pragma unroll
  for (int i = 0; i < 8; ++i){
    float4 v = *(const float4*)(modc + (size_t)b*FFD + (i*256 + t)*4);
    *(float4*)(lds + (i*256 + t)*4) = v;
  }
  float cw0 = convw[0]+convw[4]+convw[8]+convw[12];
  float cw1 = convw[1]+convw[5]+convw[9]+convw[13];
  float cw2 = convw[2]+convw[6]+convw[10]+convw[14];
  float cw3 = convw[3]+convw[7]+convw[11]+convw[15];
  float cb  = convb[0]+convb[1]+convb[2]+convb[3];
  __syncthreads();
  float im = s_im;
  float maxs = red[b], maxp = red[32+b];
  int w = t;
  for (int it = 0; it < 16; ++it){
    int h = chunk*16 + it;
    int pix = h*WD + w;
    float r_, i_, p_, q_;
    pixel_core(lds, h, w, pix, cw0, cw1, cw2, cw3, cb, wmod, wstat,
               r_, i_, p_, q_);
    float as = sqrtf(r_*r_ + i_*i_ + EPSF);
    float fs = (as/(maxs+EPSF))/(as+EPSF)*im;
    float2 A0 = *(const float2*)(wstat + (size_t)pix*2);
    float mwr = A0.x + fs*r_;
    float mwi = A0.y + fs*i_;
    float ap = sqrtf(p_*p_ + q_*q_ + EPSF);
    float fp = (ap/(maxp+EPSF))/(ap+EPSF);
    float mpr = fp*p_, mpi = fp*q_;
    float den = sqrtf(mpr*mpr + mpi*mpi + EPSF);
    out[(size_t)b*NPIX + pix] = (mwr*mpr + mwi*mpi)/den;
  }
}

// ---------- launch ----------

extern "C" void kernel_launch(void* const* d_in, const int* in_sizes, int n_in,
                              void* d_out, int out_size, void* d_ws, size_t ws_size,
                              hipStream_t stream){
  const float* x     = (const float*)d_in[0];
  const float* Win   = (const float*)d_in[1];
  const float* bin   = (const float*)d_in[2];
  const float* Wg    = (const float*)d_in[3];
  const float* bg    = (const float*)d_in[4];
  const float* Wt    = (const float*)d_in[5];
  const float* bt    = (const float*)d_in[6];
  const float* convw = (const float*)d_in[7];
  const float* convb = (const float*)d_in[8];
  const float* wstat = (const float*)d_in[9];
  const float* wmod  = (const float*)d_in[10];
  float* out = (float*)d_out;
  float* ws  = (float*)d_ws;

  // layout (floats); aliases are lifetime-disjoint:
  float* xtT   = ws;                       // dead after normgate
  float* xgT   = ws + 262144;              // dead after normgate
  float* ctx2T = ws;                       // alias xtT
  float* modc  = ws + 262144;              // alias xgT
  unsigned short* P2 = (unsigned short*)(ws + 524288);   // ctx pack
  unsigned short* P1 = (unsigned short*)(ws + 917504);   // x pack
  float* Cp    = ws + 966656;              // 4M floats, shared by G1/G2 partials
  float* red     = ws + 5160960;           // max_s[32], max_p[32]
  float* magpart = ws + 5161024;           // [32][16]

  k_prep<<<16, 256, 0, stream>>>(x, P1, red);
  // GEMM1: K=1024, KSPLIT=8 (KC=4), both weight matrices
  k_gemm_mfma<4><<<dim3(128,8,2), 256, 0, stream>>>(Win, Wg, P1,
                                                    Cp, CTXD, 8ull*FFD*32);
  k_reduce1<<<2048, 256, 0, stream>>>(Cp, bin, bg, xtT, xgT);
  k_normgate<<<128, 256, 0, stream>>>(xtT, xgT, P2);
  // GEMM2: K=8192, KSPLIT=16 (KC=16)
  k_gemm_mfma<16><<<dim3(128,16,1), 256, 0, stream>>>(Wt, Wt, P2,
                                                      Cp, FFD, 0);
  k_reduce2<<<1024, 256, 0, stream>>>(Cp, bt, ctx2T);
  k_norm512<<<512, 256, 0, stream>>>(ctx2T, modc);
  k_scan<<<512, 256, 0, stream>>>(modc, convw, convb, wmod, wstat, red, magpart);
  k_final<<<512, 256, 0, stream>>>(modc, convw, convb, wmod, wstat, red,
                                   magpart, out);
}

// Round 9
// 163.538 us; speedup vs baseline: 2.1063x; 1.0640x over previous
//
#include <hip/hip_runtime.h>
#include <cstddef>

#define NB   32
#define CTXD 1024
#define FFD  8192
#define HD   256
#define WD   256
#define NPIX 65536
#define EPSF 1e-12f

typedef __attribute__((ext_vector_type(8))) short bf16x8;
typedef __attribute__((ext_vector_type(4))) float f32x4;

// ---------- helpers ----------

__device__ __forceinline__ float ftanh(float x){
  float ax = fabsf(x);
  float e  = __expf(2.0f*ax);
  float r  = 1.0f - 2.0f*__builtin_amdgcn_rcpf(e + 1.0f);
  return copysignf(r, x);
}

__device__ __forceinline__ unsigned short f2bf(float f){
  unsigned u = __float_as_uint(f);
  unsigned r = (u + 0x7FFFu + ((u >> 16) & 1u)) >> 16;   // RTNE
  return (unsigned short)r;
}
__device__ __forceinline__ float bf2f(unsigned short s){
  return __uint_as_float((unsigned)s << 16);
}

// split f32 -> 3 bf16 terms (residual ~2^-27 relative)
__device__ __forceinline__ void split3(float f, unsigned short& s0,
                                       unsigned short& s1, unsigned short& s2){
  s0 = f2bf(f);
  float r1 = f - bf2f(s0);
  s1 = f2bf(r1);
  float r2 = r1 - bf2f(s1);
  s2 = f2bf(r2);
}

// async global->LDS, 16B per lane; dst must be wave-uniform (lane*16 implicit)
__device__ __forceinline__ void gload_lds16(const float* g, float* l){
  __builtin_amdgcn_global_load_lds(
      (__attribute__((address_space(1))) void*)const_cast<float*>(g),
      (__attribute__((address_space(3))) void*)l, 16, 0, 0);
}

__device__ __forceinline__ void block_reduce4(float& a, float& b, float& c, float& d){
  for (int off = 32; off > 0; off >>= 1){
    a += __shfl_down(a, off); b += __shfl_down(b, off);
    c += __shfl_down(c, off); d += __shfl_down(d, off);
  }
  __shared__ float lds[16];
  int wid = threadIdx.x >> 6, lane = threadIdx.x & 63;
  if (lane == 0){ lds[wid*4+0]=a; lds[wid*4+1]=b; lds[wid*4+2]=c; lds[wid*4+3]=d; }
  __syncthreads();
  a = (lds[0]+lds[4])+(lds[8]+lds[12]);
  b = (lds[1]+lds[5])+(lds[9]+lds[13]);
  c = (lds[2]+lds[6])+(lds[10]+lds[14]);
  d = (lds[3]+lds[7])+(lds[11]+lds[15]);
}

// per-pixel recompute core shared by k_scan / k_final (must stay identical)
__device__ __forceinline__ void pixel_core(
    const float* __restrict__ lds, int h, int w, int pix,
    float cw0, float cw1, float cw2, float cw3, float cb,
    const float* __restrict__ wmod, const float* __restrict__ wstat,
    float& r_, float& i_, float& p_, float& q_){
  float sk[4];
  #pragma unroll
  for (int k = 0; k < 4; ++k){
    float acc = 0.f;
    #pragma unroll
    for (int r = 0; r < 4; ++r){
      int kr = k*4 + r;
      float u  = lds[kr*512 + h];
      float vv = lds[kr*512 + 256 + w];
      float tt = ftanh(u*vv);
      float cwr = (r==0)?cw0:(r==1)?cw1:(r==2)?cw2:cw3;
      acc += (k==0) ? cwr*tt : tt;
    }
    sk[k] = acc;
  }
  sk[0] += cb;
  float m0 = sk[0]*wmod[0*NPIX+pix];
  float m1 = sk[1]*wmod[1*NPIX+pix];
  float m2 = sk[2]*wmod[2*NPIX+pix];
  float m3 = sk[3]*wmod[3*NPIX+pix];
  float2 A1 = *(const float2*)(wstat + (size_t)(NPIX + pix)*2);
  r_ = A1.x*m0 - A1.y*m1;
  i_ = A1.x*m1 - A1.y*m0;
  p_ = m2; q_ = m3;
}

// ---------- kernels ----------

// split x [32][1024] f32 -> packed B-fragment layout, zero red[]
__global__ __launch_bounds__(256) void k_prep(
    const float* __restrict__ x, unsigned short* __restrict__ P,
    float* __restrict__ red){
  int g = blockIdx.x*256 + threadIdx.x;      // 4096 = 32 rows x 128 groups
  if (g < 64) red[g] = 0.0f;
  int b = g >> 7, grp = g & 127;
  int koff = grp*8;
  int c = grp >> 2, kg = grp & 3;
  const float* src = x + (size_t)b*CTXD + koff;
  float4 v0 = *(const float4*)(src), v1 = *(const float4*)(src+4);
  float vv[8] = {v0.x,v0.y,v0.z,v0.w,v1.x,v1.y,v1.z,v1.w};
  bf16x8 a0, a1, a2;
  #pragma unroll
  for (int e = 0; e < 8; ++e){
    unsigned short s0,s1,s2; split3(vv[e],s0,s1,s2);
    a0[e]=(short)s0; a1[e]=(short)s1; a2[e]=(short)s2;
  }
  size_t base = (size_t)c*3072 + (b>>4)*512 + kg*128 + (b&15)*8;
  *(bf16x8*)(P + base)        = a0;
  *(bf16x8*)(P + base + 1024) = a1;
  *(bf16x8*)(P + base + 2048) = a2;
}

// Register-direct split-bf16 MFMA GEMM (used for GEMM1, K=1024).
template<int KC>
__global__ __launch_bounds__(256) void k_gemm_mfma(
    const float* __restrict__ W0, const float* __restrict__ W1,
    const unsigned short* __restrict__ BP,
    float* __restrict__ Cp, int K, size_t zstride){
  const float* __restrict__ W = blockIdx.z ? W1 : W0;
  int wave = threadIdx.x >> 6;
  int lane = threadIdx.x & 63;
  int f0   = blockIdx.x*64 + wave*16;
  int kc   = blockIdx.y;
  int row  = lane & 15;
  int kg   = lane >> 4;
  int rot  = blockIdx.x & (KC-1);
  const float* Wb = W + (size_t)(f0+row)*K + kc*KC*32 + kg*8;
  const unsigned short* Bb = BP + (size_t)kc*KC*3072 + kg*128 + row*8;
  f32x4 acc0={0.f,0.f,0.f,0.f}, acc1={0.f,0.f,0.f,0.f};
  const float* wp = Wb + rot*32;
  float4 w0 = *(const float4*)(wp), w1 = *(const float4*)(wp+4);
  for (int c = 0; c < KC; ++c){
    int rc = (c + rot) & (KC-1);
    const unsigned short* bp = Bb + (size_t)rc*3072;
    bf16x8 b0h0 = *(const bf16x8*)(bp);
    bf16x8 b0h1 = *(const bf16x8*)(bp +  512);
    bf16x8 b1h0 = *(const bf16x8*)(bp + 1024);
    bf16x8 b1h1 = *(const bf16x8*)(bp + 1536);
    bf16x8 b2h0 = *(const bf16x8*)(bp + 2048);
    bf16x8 b2h1 = *(const bf16x8*)(bp + 2560);
    float4 cw0 = w0, cw1 = w1;
    if (c + 1 < KC){
      int rn = (c + 1 + rot) & (KC-1);
      wp = Wb + rn*32;
      w0 = *(const float4*)(wp); w1 = *(const float4*)(wp+4);
    }
    bf16x8 a0, a1, a2;
    float wv[8] = {cw0.x,cw0.y,cw0.z,cw0.w,cw1.x,cw1.y,cw1.z,cw1.w};
    #pragma unroll
    for (int e = 0; e < 8; ++e){
      unsigned short s0,s1,s2; split3(wv[e],s0,s1,s2);
      a0[e]=(short)s0; a1[e]=(short)s1; a2[e]=(short)s2;
    }
    acc0 = __builtin_amdgcn_mfma_f32_16x16x32_bf16(a0, b0h0, acc0, 0,0,0);
    acc1 = __builtin_amdgcn_mfma_f32_16x16x32_bf16(a0, b0h1, acc1, 0,0,0);
    acc0 = __builtin_amdgcn_mfma_f32_16x16x32_bf16(a0, b1h0, acc0, 0,0,0);
    acc1 = __builtin_amdgcn_mfma_f32_16x16x32_bf16(a0, b1h1, acc1, 0,0,0);
    acc0 = __builtin_amdgcn_mfma_f32_16x16x32_bf16(a1, b0h0, acc0, 0,0,0);
    acc1 = __builtin_amdgcn_mfma_f32_16x16x32_bf16(a1, b0h1, acc1, 0,0,0);
    acc0 = __builtin_amdgcn_mfma_f32_16x16x32_bf16(a0, b2h0, acc0, 0,0,0);
    acc1 = __builtin_amdgcn_mfma_f32_16x16x32_bf16(a0, b2h1, acc1, 0,0,0);
    acc0 = __builtin_amdgcn_mfma_f32_16x16x32_bf16(a1, b1h0, acc0, 0,0,0);
    acc1 = __builtin_amdgcn_mfma_f32_16x16x32_bf16(a1, b1h1, acc1, 0,0,0);
    acc0 = __builtin_amdgcn_mfma_f32_16x16x32_bf16(a2, b0h0, acc0, 0,0,0);
    acc1 = __builtin_amdgcn_mfma_f32_16x16x32_bf16(a2, b0h1, acc1, 0,0,0);
  }
  float* __restrict__ C = Cp + (size_t)blockIdx.z*zstride + (size_t)kc*(FFD*32);
  #pragma unroll
  for (int r = 0; r < 4; ++r){
    int f = f0 + kg*4 + r;
    C[(size_t)f*32 + row]      = acc0[r];
    C[(size_t)f*32 + 16 + row] = acc1[r];
  }
}

// LDS-staged streaming split-bf16 MFMA GEMM (GEMM2, K=8192).
// Block: 64 features x one kc-slice (STEPS steps of BK=64 k).
// W staged via async global_load_lds (4KB/wave/step, contiguous rows);
// B (ctx pack) register-loaded from L2. One barrier per step.
template<int STEPS>
__global__ __launch_bounds__(256) void k_gemm_lds(
    const float* __restrict__ W, const unsigned short* __restrict__ BP,
    float* __restrict__ Cp, int K){
  __shared__ float tile[2][4096];          // 2 x 64 rows x 64 k (16KB each)
  const int t    = threadIdx.x;
  const int wv   = t >> 6, lane = t & 63;
  const int f0   = blockIdx.x * 64;
  const int kc   = blockIdx.y;
  const int row  = lane & 15, kg = lane >> 4;
  const int srot = blockIdx.x & (STEPS - 1);   // L2-channel decorrelation
  const size_t kslice = (size_t)kc * STEPS * 64;

  f32x4 acc0 = {0.f,0.f,0.f,0.f}, acc1 = {0.f,0.f,0.f,0.f};

  // stage step s of the kc-slice into tile[buf]: 16 calls (4/wave), each
  // 1KB = 4 rows x 256B, perfectly line-covered; LDS dest linear row-major.
  auto stage = [&](int buf, int s){
    const size_t kbase = kslice + (size_t)s*64;
    #pragma unroll
    for (int i = 0; i < 4; ++i){
      int r = wv*16 + i*4 + (lane >> 4);
      const float* gsrc = W + (size_t)(f0 + r)*K + kbase + (lane & 15)*4;
      gload_lds16(gsrc, &tile[buf][(wv*16 + i*4)*64]);
    }
  };

  int cur = 0;
  stage(0, srot);
  __syncthreads();                          // drain (compiler vmcnt(0))

  for (int s = 0; s < STEPS; ++s){
    const int sc = (s + srot) & (STEPS - 1);
    // B loads for both chunks FIRST (L2-hot; before staging so their
    // vmcnt wait does not force the async staging to drain)
    const int k0 = kc*STEPS*2 + sc*2;
    const unsigned short* bp0 = BP + (size_t)k0*3072     + kg*128 + row*8;
    const unsigned short* bp1 = BP + (size_t)(k0+1)*3072 + kg*128 + row*8;
    bf16x8 c0b0h0 = *(const bf16x8*)(bp0);
    bf16x8 c0b0h1 = *(const bf16x8*)(bp0 +  512);
    bf16x8 c0b1h0 = *(const bf16x8*)(bp0 + 1024);
    bf16x8 c0b1h1 = *(const bf16x8*)(bp0 + 1536);
    bf16x8 c0b2h0 = *(const bf16x8*)(bp0 + 2048);
    bf16x8 c0b2h1 = *(const bf16x8*)(bp0 + 2560);
    bf16x8 c1b0h0 = *(const bf16x8*)(bp1);
    bf16x8 c1b0h1 = *(const bf16x8*)(bp1 +  512);
    bf16x8 c1b1h0 = *(const bf16x8*)(bp1 + 1024);
    bf16x8 c1b1h1 = *(const bf16x8*)(bp1 + 1536);
    bf16x8 c1b2h0 = *(const bf16x8*)(bp1 + 2048);
    bf16x8 c1b2h1 = *(const bf16x8*)(bp1 + 2560);
    // issue next step's staging (async; completes under this step's compute)
    if (s + 1 < STEPS) stage(cur ^ 1, (s + 1 + srot) & (STEPS - 1));
    // compute the two K=32 chunks from LDS
    #pragma unroll
    for (int c = 0; c < 2; ++c){
      const float* wp = &tile[cur][(wv*16 + row)*64 + c*32 + kg*8];
      float4 w0 = *(const float4*)(wp);
      float4 w1 = *(const float4*)(wp + 4);
      bf16x8 a0, a1, a2;
      float wv8[8] = {w0.x,w0.y,w0.z,w0.w,w1.x,w1.y,w1.z,w1.w};
      #pragma unroll
      for (int e = 0; e < 8; ++e){
        unsigned short s0,s1,s2; split3(wv8[e],s0,s1,s2);
        a0[e]=(short)s0; a1[e]=(short)s1; a2[e]=(short)s2;
      }
      bf16x8 b0h0 = c ? c1b0h0 : c0b0h0, b0h1 = c ? c1b0h1 : c0b0h1;
      bf16x8 b1h0 = c ? c1b1h0 : c0b1h0, b1h1 = c ? c1b1h1 : c0b1h1;
      bf16x8 b2h0 = c ? c1b2h0 : c0b2h0, b2h1 = c ? c1b2h1 : c0b2h1;
      acc0 = __builtin_amdgcn_mfma_f32_16x16x32_bf16(a0, b0h0, acc0, 0,0,0);
      acc1 = __builtin_amdgcn_mfma_f32_16x16x32_bf16(a0, b0h1, acc1, 0,0,0);
      acc0 = __builtin_amdgcn_mfma_f32_16x16x32_bf16(a0, b1h0, acc0, 0,0,0);
      acc1 = __builtin_amdgcn_mfma_f32_16x16x32_bf16(a0, b1h1, acc1, 0,0,0);
      acc0 = __builtin_amdgcn_mfma_f32_16x16x32_bf16(a1, b0h0, acc0, 0,0,0);
      acc1 = __builtin_amdgcn_mfma_f32_16x16x32_bf16(a1, b0h1, acc1, 0,0,0);
      acc0 = __builtin_amdgcn_mfma_f32_16x16x32_bf16(a0, b2h0, acc0, 0,0,0);
      acc1 = __builtin_amdgcn_mfma_f32_16x16x32_bf16(a0, b2h1, acc1, 0,0,0);
      acc0 = __builtin_amdgcn_mfma_f32_16x16x32_bf16(a1, b1h0, acc0, 0,0,0);
      acc1 = __builtin_amdgcn_mfma_f32_16x16x32_bf16(a1, b1h1, acc1, 0,0,0);
      acc0 = __builtin_amdgcn_mfma_f32_16x16x32_bf16(a2, b0h0, acc0, 0,0,0);
      acc1 = __builtin_amdgcn_mfma_f32_16x16x32_bf16(a2, b0h1, acc1, 0,0,0);
    }
    __syncthreads();                       // drains this step's staging
    cur ^= 1;
  }

  float* __restrict__ C = Cp + (size_t)kc*(FFD*32);
  #pragma unroll
  for (int r = 0; r < 4; ++r){
    int f = f0 + wv*16 + kg*4 + r;
    C[(size_t)f*32 + row]      = acc0[r];
    C[(size_t)f*32 + 16 + row] = acc1[r];
  }
}

// reduce for GEMM1 (both matrices), S=8
__global__ __launch_bounds__(256) void k_reduce1(
    const float* __restrict__ Cp, const float* __restrict__ bin,
    const float* __restrict__ bg, float* __restrict__ xtT,
    float* __restrict__ xgT){
  int g = blockIdx.x*256 + threadIdx.x;          // 524288
  int m = g >> 18, idx = g & 262143;
  int f = idx >> 5;
  const float* __restrict__ cp = Cp + (size_t)m*(8ull*FFD*32);
  float s = (m ? bg : bin)[f];
  #pragma unroll
  for (int sI = 0; sI < 8; ++sI) s += cp[(size_t)sI*(FFD*32) + idx];
  (m ? xgT : xtT)[idx] = s;
}

// reduce for GEMM2, S=16
__global__ __launch_bounds__(256) void k_reduce2(
    const float* __restrict__ Cp, const float* __restrict__ bias,
    float* __restrict__ outT){
  int g = blockIdx.x*256 + threadIdx.x;          // 262144
  int f = g >> 5;
  float s = bias[f];
  #pragma unroll
  for (int sI = 0; sI < 16; ++sI) s += Cp[(size_t)sI*(FFD*32) + g];
  outT[g] = s;
}

// norm over 2048-groups (ddof=1); ctx = nt*tanh(ng) -> packed B-fragment layout
__global__ __launch_bounds__(256) void k_normgate(
    const float* __restrict__ xtT, const float* __restrict__ xgT,
    unsigned short* __restrict__ P){
  int b = blockIdx.x >> 2, g4 = blockIdx.x & 3;
  int t = threadIdx.x;
  int f8 = g4*2048 + t*8;
  float vt[8], vg[8];
  float st=0.f, sst=0.f, sg=0.f, ssg=0.f;
  #pragma unroll
  for (int i = 0; i < 8; ++i){
    int f = f8 + i;
    float a = xtT[(size_t)f*NB + b];
    float c = xgT[(size_t)f*NB + b];
    vt[i]=a; vg[i]=c;
    st += a; sst += a*a; sg += c; ssg += c*c;
  }
  block_reduce4(st, sst, sg, ssg);
  float mt = st * (1.0f/2048.0f);
  float it = rsqrtf((sst - st*mt) * (1.0f/2047.0f) + EPSF);
  float mg = sg * (1.0f/2048.0f);
  float ig = rsqrtf((ssg - sg*mg) * (1.0f/2047.0f) + EPSF);
  bf16x8 a0, a1, a2;
  #pragma unroll
  for (int i = 0; i < 8; ++i){
    float nt = (vt[i]-mt)*it;
    float ng = (vg[i]-mg)*ig;
    float cv = nt * ftanh(ng);
    unsigned short s0,s1,s2; split3(cv,s0,s1,s2);
    a0[i]=(short)s0; a1[i]=(short)s1; a2[i]=(short)s2;
  }
  int c2 = f8 >> 5, kg = (f8 >> 3) & 3;
  size_t base = (size_t)c2*3072 + (b>>4)*512 + kg*128 + (b&15)*8;
  *(bf16x8*)(P + base)        = a0;
  *(bf16x8*)(P + base + 1024) = a1;
  *(bf16x8*)(P + base + 2048) = a2;
}

// norm over 512-groups (ddof=1) -> modc [B][16][512]
__global__ __launch_bounds__(256) void k_norm512(
    const float* __restrict__ ctx2T, float* __restrict__ modc){
  int b = blockIdx.x >> 4, kr = blockIdx.x & 15;
  int t = threadIdx.x;
  int base = kr*512;
  float v0 = ctx2T[(base + t      )*NB + b];
  float v1 = ctx2T[(base + 256 + t)*NB + b];
  float s = v0+v1, ss = v0*v0 + v1*v1, d0=0.f, d1=0.f;
  block_reduce4(s, ss, d0, d1);
  float m   = s * (1.0f/512.0f);
  float inv = rsqrtf((ss - s*m) * (1.0f/511.0f) + EPSF);
  modc[b*FFD + base + t      ] = (v0-m)*inv;
  modc[b*FFD + base + 256 + t] = (v1-m)*inv;
}

// scan pass: per-batch max_s/max_p + Sigma|v_s| partials. No plane stores.
__global__ __launch_bounds__(256) void k_scan(
    const float* __restrict__ modc,
    const float* __restrict__ convw, const float* __restrict__ convb,
    const float* __restrict__ wmod, const float* __restrict__ wstat,
    float* __restrict__ red, float* __restrict__ magpart){
  int b = blockIdx.x >> 4, chunk = blockIdx.x & 15;
  int t = threadIdx.x;
  __shared__ float lds[16*512];
  #pragma unroll
  for (int i = 0; i < 8; ++i){
    float4 v = *(const float4*)(modc + (size_t)b*FFD + (i*256 + t)*4);
    *(float4*)(lds + (i*256 + t)*4) = v;
  }
  float cw0 = convw[0]+convw[4]+convw[8]+convw[12];
  float cw1 = convw[1]+convw[5]+convw[9]+convw[13];
  float cw2 = convw[2]+convw[6]+convw[10]+convw[14];
  float cw3 = convw[3]+convw[7]+convw[11]+convw[15];
  float cb  = convb[0]+convb[1]+convb[2]+convb[3];
  __syncthreads();
  int w = t;
  float mxs = 0.f, mxp = 0.f, sas = 0.f;
  for (int it = 0; it < 16; ++it){
    int h = chunk*16 + it;
    int pix = h*WD + w;
    float r_, i_, p_, q_;
    pixel_core(lds, h, w, pix, cw0, cw1, cw2, cw3, cb, wmod, wstat,
               r_, i_, p_, q_);
    float as = sqrtf(r_*r_ + i_*i_ + EPSF);
    float ap = sqrtf(p_*p_ + q_*q_ + EPSF);
    mxs = fmaxf(mxs, as); mxp = fmaxf(mxp, ap);
    sas += as;
  }
  for (int off = 32; off > 0; off >>= 1){
    mxs = fmaxf(mxs, __shfl_down(mxs, off));
    mxp = fmaxf(mxp, __shfl_down(mxp, off));
    sas += __shfl_down(sas, off);
  }
  __shared__ float lred[12];
  int wid = t >> 6, lane = t & 63;
  if (lane == 0){ lred[wid] = mxs; lred[4+wid] = mxp; lred[8+wid] = sas; }
  __syncthreads();
  if (t == 0){
    float a = fmaxf(fmaxf(lred[0],lred[1]), fmaxf(lred[2],lred[3]));
    float p = fmaxf(fmaxf(lred[4],lred[5]), fmaxf(lred[6],lred[7]));
    float s = (lred[8]+lred[9])+(lred[10]+lred[11]);
    atomicMax((int*)&red[b],    __float_as_int(a));
    atomicMax((int*)&red[32+b], __float_as_int(p));
    magpart[b*16 + chunk] = s;
  }
}

// final: recompute pixels, combine with per-batch stats -> out
__global__ __launch_bounds__(256) void k_final(
    const float* __restrict__ modc,
    const float* __restrict__ convw, const float* __restrict__ convb,
    const float* __restrict__ wmod, const float* __restrict__ wstat,
    const float* __restrict__ red, const float* __restrict__ magpart,
    float* __restrict__ out){
  int b = blockIdx.x >> 4, chunk = blockIdx.x & 15;
  int t = threadIdx.x;
  __shared__ float lds[16*512];
  __shared__ float s_im;
  if (t < 16){
    float v = magpart[b*16 + t];
    for (int off = 8; off > 0; off >>= 1) v += __shfl_down(v, off);
    if (t == 0){
      float maxs = red[b];
      s_im = rsqrtf(v*(1.0f/65536.0f)/(maxs + EPSF) + EPSF);
    }
  }
  #pragma unroll
  for (int i = 0; i < 8; ++i){
    float4 v = *(const float4*)(modc + (size_t)b*FFD + (i*256 + t)*4);
    *(float4*)(lds + (i*256 + t)*4) = v;
  }
  float cw0 = convw[0]+convw[4]+convw[8]+convw[12];
  float cw1 = convw[1]+convw[5]+convw[9]+convw[13];
  float cw2 = convw[2]+convw[6]+convw[10]+convw[14];
  float cw3 = convw[3]+convw[7]+convw[11]+convw[15];
  float cb  = convb[0]+convb[1]+convb[2]+convb[3];
  __syncthreads();
  float im = s_im;
  float maxs = red[b], maxp = red[32+b];
  int w = t;
  for (int it = 0; it < 16; ++it){
    int h = chunk*16 + it;
    int pix = h*WD + w;
    float r_, i_, p_, q_;
    pixel_core(lds, h, w, pix, cw0, cw1, cw2, cw3, cb, wmod, wstat,
               r_, i_, p_, q_);
    float as = sqrtf(r_*r_ + i_*i_ + EPSF);
    float fs = (as/(maxs+EPSF))/(as+EPSF)*im;
    float2 A0 = *(const float2*)(wstat + (size_t)pix*2);
    float mwr = A0.x + fs*r_;
    float mwi = A0.y + fs*i_;
    float ap = sqrtf(p_*p_ + q_*q_ + EPSF);
    float fp = (ap/(maxp+EPSF))/(ap+EPSF);
    float mpr = fp*p_, mpi = fp*q_;
    float den = sqrtf(mpr*mpr + mpi*mpi + EPSF);
    out[(size_t)b*NPIX + pix] = (mwr*mpr + mwi*mpi)/den;
  }
}

// ---------- launch ----------

extern "C" void kernel_launch(void* const* d_in, const int* in_sizes, int n_in,
                              void* d_out, int out_size, void* d_ws, size_t ws_size,
                              hipStream_t stream){
  const float* x     = (const float*)d_in[0];
  const float* Win   = (const float*)d_in[1];
  const float* bin   = (const float*)d_in[2];
  const float* Wg    = (const float*)d_in[3];
  const float* bg    = (const float*)d_in[4];
  const float* Wt    = (const float*)d_in[5];
  const float* bt    = (const float*)d_in[6];
  const float* convw = (const float*)d_in[7];
  const float* convb = (const float*)d_in[8];
  const float* wstat = (const float*)d_in[9];
  const float* wmod  = (const float*)d_in[10];
  float* out = (float*)d_out;
  float* ws  = (float*)d_ws;

  // layout (floats); aliases are lifetime-disjoint:
  float* xtT   = ws;                       // dead after normgate
  float* xgT   = ws + 262144;              // dead after normgate
  float* ctx2T = ws;                       // alias xtT
  float* modc  = ws + 262144;              // alias xgT
  unsigned short* P2 = (unsigned short*)(ws + 524288);   // ctx pack
  unsigned short* P1 = (unsigned short*)(ws + 917504);   // x pack
  float* Cp    = ws + 966656;              // 4M floats, shared by G1/G2 partials
  float* red     = ws + 5160960;           // max_s[32], max_p[32]
  float* magpart = ws + 5161024;           // [32][16]

  k_prep<<<16, 256, 0, stream>>>(x, P1, red);
  // GEMM1: K=1024, KSPLIT=8 (KC=4), both weight matrices (register version)
  k_gemm_mfma<4><<<dim3(128,8,2), 256, 0, stream>>>(Win, Wg, P1,
                                                    Cp, CTXD, 8ull*FFD*32);
  k_reduce1<<<2048, 256, 0, stream>>>(Cp, bin, bg, xtT, xgT);
  k_normgate<<<128, 256, 0, stream>>>(xtT, xgT, P2);
  // GEMM2: K=8192, KSPLIT=16, LDS-staged streaming version (STEPS=8, BK=64)
  k_gemm_lds<8><<<dim3(128,16), 256, 0, stream>>>(Wt, P2, Cp, FFD);
  k_reduce2<<<1024, 256, 0, stream>>>(Cp, bt, ctx2T);
  k_norm512<<<512, 256, 0, stream>>>(ctx2T, modc);
  k_scan<<<512, 256, 0, stream>>>(modc, convw, convb, wmod, wstat, red, magpart);
  k_final<<<512, 256, 0, stream>>>(modc, convw, convb, wmod, wstat, red,
                                   magpart, out);
}